// Round 15
// baseline (242.039 us; speedup 1.0000x reference)
//
#include <hip/hip_runtime.h>
#include <math.h>

#define BB 2
#define SS 2048
#define DD 1024
#define HH 16
#define HDD 64
static constexpr float EPS = 1e-6f;

typedef __bf16 bf16x8 __attribute__((ext_vector_type(8)));
typedef __bf16 bf16x4 __attribute__((ext_vector_type(4)));
typedef float f32x4 __attribute__((ext_vector_type(4)));
typedef __attribute__((address_space(1))) const unsigned int gas_u32;
typedef __attribute__((address_space(3))) unsigned int las_u32;

__device__ __forceinline__ unsigned short f2bf(float f) {
    unsigned int u = __float_as_uint(f);
    u = (u + 0x7FFFu + ((u >> 16) & 1u)) >> 16;   // round-to-nearest-even
    return (unsigned short)u;
}

__device__ __forceinline__ float b2f(unsigned short u) {
    return __uint_as_float((unsigned int)u << 16);
}

__device__ __forceinline__ uint2 pack4bf(float a, float b, float c, float d) {
    bf16x4 v;
    v[0] = (__bf16)a; v[1] = (__bf16)b; v[2] = (__bf16)c; v[3] = (__bf16)d;
    return *(uint2*)&v;
}

__device__ __forceinline__ void async_ld16(const unsigned short* g, unsigned short* l) {
    __builtin_amdgcn_global_load_lds((gas_u32*)g, (las_u32*)l, 16, 0, 0);
}

// ---------------------------------------------------------------------------
// Kernel 0: cast + transpose weights: w[K][N] fp32 -> wt[N][K] bf16
// ---------------------------------------------------------------------------
__global__ __launch_bounds__(256) void cast_transpose(const float* __restrict__ w,
                                                      unsigned short* __restrict__ wt,
                                                      int K, int N) {
    __shared__ float tile[32][36];
    const int n0 = blockIdx.x * 32;
    const int k0 = blockIdx.y * 32;
    const int t = threadIdx.x;
    const int r = t >> 3;
    const int c = (t & 7) * 4;
    *(float4*)&tile[r][c] = *(const float4*)(w + (size_t)(k0 + r) * N + n0 + c);
    __syncthreads();
    unsigned short o[4];
#pragma unroll
    for (int i = 0; i < 4; i++) o[i] = f2bf(tile[c + i][r]);
    *(uint2*)(wt + (size_t)(n0 + r) * K + k0 + c) = *(uint2*)o;
}

// ---------------------------------------------------------------------------
// Kernel 0b: RoPE tables: ctab/stab[s][i] = cos/sin(s * 10000^(-i/32))
// ---------------------------------------------------------------------------
__global__ __launch_bounds__(256) void rope_tables(float* __restrict__ ctab,
                                                   float* __restrict__ stab) {
    const int idx = blockIdx.x * 256 + threadIdx.x;   // 0..65535
    const int s = idx >> 5;
    const int i = idx & 31;
    const float ang = (float)s * exp2f(-(float)i * (13.287712379549449f / 32.f));
    ctab[idx] = cosf(ang);
    stab[idx] = sinf(ang);
}

// ---------------------------------------------------------------------------
// Kernel 1: LayerNorm rows of x [4096,1024] -> xn (bf16)
// ---------------------------------------------------------------------------
__global__ __launch_bounds__(256) void ln_kernel(const float* __restrict__ x,
                                                 const float* __restrict__ scale,
                                                 const float* __restrict__ bias,
                                                 unsigned short* __restrict__ xn) {
    __shared__ float red[4];
    const int row = blockIdx.x;
    const int t = threadIdx.x;
    const float* xr = x + (size_t)row * DD + t * 4;

    float4 v = *(const float4*)xr;
    float s = v.x + v.y + v.z + v.w;
#pragma unroll
    for (int o = 32; o; o >>= 1) s += __shfl_xor(s, o);
    if ((t & 63) == 0) red[t >> 6] = s;
    __syncthreads();
    const float mu = (red[0] + red[1] + red[2] + red[3]) * (1.f / DD);

    float4 d = {v.x - mu, v.y - mu, v.z - mu, v.w - mu};
    float sq = d.x * d.x + d.y * d.y + d.z * d.z + d.w * d.w;
#pragma unroll
    for (int o = 32; o; o >>= 1) sq += __shfl_xor(sq, o);
    __syncthreads();
    if ((t & 63) == 0) red[t >> 6] = sq;
    __syncthreads();
    const float var = (red[0] + red[1] + red[2] + red[3]) * (1.f / DD);
    const float rstd = rsqrtf(var + EPS);

    const float4 sc = *(const float4*)(scale + t * 4);
    const float4 bi = *(const float4*)(bias + t * 4);
    unsigned short o[4];
    o[0] = f2bf(d.x * rstd * sc.x + bi.x);
    o[1] = f2bf(d.y * rstd * sc.y + bi.y);
    o[2] = f2bf(d.z * rstd * sc.z + bi.z);
    o[3] = f2bf(d.w * rstd * sc.w + bi.w);
    *(uint2*)(xn + (size_t)row * DD + t * 4) = *(uint2*)o;
}

// ---------------------------------------------------------------------------
// Kernel 2: out-projection GEMM, 64x128 tile (2 blocks/CU):
// C[M,N] = A[M,K] @ Bt[N,K]^T + bias. 4 waves; wave wv owns 64 x 32.
// ---------------------------------------------------------------------------
__global__ __launch_bounds__(256) void gemm_out_64(const unsigned short* __restrict__ A,
                                                   const unsigned short* __restrict__ Bt,
                                                   const float* __restrict__ bias,
                                                   float* __restrict__ C,
                                                   int M, int N, int K) {
    __shared__ __align__(16) unsigned short As[64][32];    // 4 KB
    __shared__ __align__(16) unsigned short Bs[128][32];   // 8 KB

    const int bm = blockIdx.y * 64;
    const int bn = blockIdx.x * 128;
    const int t = threadIdx.x;
    const int wv = t >> 6;
    const int ln = t & 63;
    const int m16 = ln & 15;
    const int quad = ln >> 4;
    const int wn = wv * 32;

    f32x4 acc[4][2];
#pragma unroll
    for (int i = 0; i < 4; i++)
#pragma unroll
        for (int j = 0; j < 2; j++) acc[i][j] = (f32x4){0.f, 0.f, 0.f, 0.f};

    const int srow = ln >> 2;
    const int sk = (ln & 3) * 8;
    const unsigned short* aptr = A + (size_t)(bm + wv * 16 + srow) * K + sk;
    const unsigned short* bptr0 = Bt + (size_t)(bn + wv * 32 + srow) * K + sk;
    const unsigned short* bptr1 = Bt + (size_t)(bn + wv * 32 + 16 + srow) * K + sk;
    unsigned short* al = &As[wv * 16][0];
    unsigned short* bl0 = &Bs[wv * 32][0];
    unsigned short* bl1 = &Bs[wv * 32 + 16][0];

    for (int k0 = 0; k0 < K; k0 += 32) {
        __syncthreads();
        async_ld16(aptr, al);
        async_ld16(bptr0, bl0);
        async_ld16(bptr1, bl1);
        __syncthreads();

        bf16x8 af[4], bf[2];
#pragma unroll
        for (int i = 0; i < 4; i++)
            af[i] = *(const bf16x8*)&As[i * 16 + m16][quad * 8];
#pragma unroll
        for (int j = 0; j < 2; j++)
            bf[j] = *(const bf16x8*)&Bs[wn + j * 16 + m16][quad * 8];
#pragma unroll
        for (int i = 0; i < 4; i++)
#pragma unroll
            for (int j = 0; j < 2; j++)
                acc[i][j] = __builtin_amdgcn_mfma_f32_16x16x32_bf16(af[i], bf[j], acc[i][j], 0, 0, 0);

        aptr += 32;
        bptr0 += 32;
        bptr1 += 32;
    }

#pragma unroll
    for (int j = 0; j < 2; j++) {
        const int n = bn + wn + j * 16 + m16;
        const float bv = bias[n];
#pragma unroll
        for (int i = 0; i < 4; i++) {
            float* cp = C + (size_t)(bm + i * 16 + quad * 4) * N + n;
#pragma unroll
            for (int r = 0; r < 4; r++)
                cp[(size_t)r * N] = acc[i][j][r] + bv;
        }
    }
}

// ---------------------------------------------------------------------------
// Kernel 2b: fused QKV GEMM: xn @ w_qkvT + b, then per-head LN + RoPE in the
// epilogue, writing qt/kt/vt bf16 in [b,h,s,d] directly (no fp32 qkv buffer).
// ---------------------------------------------------------------------------
__global__ __launch_bounds__(256) void gemm_qkv_fused(const unsigned short* __restrict__ A,
                                                      const unsigned short* __restrict__ Bt,
                                                      const float* __restrict__ bias,
                                                      const float* __restrict__ q_scale,
                                                      const float* __restrict__ k_scale,
                                                      const float* __restrict__ ctab,
                                                      const float* __restrict__ stab,
                                                      unsigned short* __restrict__ qt,
                                                      unsigned short* __restrict__ kt,
                                                      unsigned short* __restrict__ vt,
                                                      int K) {
    __shared__ __align__(16) unsigned short As[128][32];
    __shared__ __align__(16) unsigned short Bs[128][32];

    const int bm = blockIdx.y * 128;
    const int bn = blockIdx.x * 128;
    const int t = threadIdx.x;
    const int wv = t >> 6;
    const int ln = t & 63;
    const int m16 = ln & 15;
    const int quad = ln >> 4;
    const int wm = (wv >> 1) * 64;
    const int wn = (wv & 1) * 64;

    f32x4 acc[4][4];
#pragma unroll
    for (int i = 0; i < 4; i++)
#pragma unroll
        for (int j = 0; j < 4; j++) acc[i][j] = (f32x4){0.f, 0.f, 0.f, 0.f};

    const int srow = wv * 32 + (ln >> 2);
    const int sk = (ln & 3) * 8;
    const unsigned short* aptr = A + (size_t)(bm + srow) * K + sk;
    const unsigned short* bptr = Bt + (size_t)(bn + srow) * K + sk;
    unsigned short* al0 = &As[wv * 32][0];
    unsigned short* al1 = &As[wv * 32 + 16][0];
    unsigned short* bl0 = &Bs[wv * 32][0];
    unsigned short* bl1 = &Bs[wv * 32 + 16][0];

    for (int k0 = 0; k0 < K; k0 += 32) {
        __syncthreads();
        async_ld16(aptr, al0);
        async_ld16(aptr + 16 * (size_t)K, al1);
        async_ld16(bptr, bl0);
        async_ld16(bptr + 16 * (size_t)K, bl1);
        __syncthreads();

        bf16x8 af[4], bf[4];
#pragma unroll
        for (int i = 0; i < 4; i++)
            af[i] = *(const bf16x8*)&As[wm + i * 16 + m16][quad * 8];
#pragma unroll
        for (int j = 0; j < 4; j++)
            bf[j] = *(const bf16x8*)&Bs[wn + j * 16 + m16][quad * 8];
#pragma unroll
        for (int i = 0; i < 4; i++)
#pragma unroll
            for (int j = 0; j < 4; j++)
                acc[i][j] = __builtin_amdgcn_mfma_f32_16x16x32_bf16(af[i], bf[j], acc[i][j], 0, 0, 0);

        aptr += 32;
        bptr += 32;
    }

    // -------- fused epilogue --------
    const int type = bn >> 10;                       // 0=Q, 1=K, 2=V
    const int h = ((bn & 1023) + wn) >> 6;           // this wave's head
    const int rowbase = bm + wm;

    if (type == 2) {
        // V: bias + cast + store [b,h,s,d]
        float bv[4];
#pragma unroll
        for (int j = 0; j < 4; j++) bv[j] = bias[bn + wn + j * 16 + m16];
#pragma unroll
        for (int i = 0; i < 4; i++) {
#pragma unroll
            for (int r = 0; r < 4; r++) {
                const int R = rowbase + i * 16 + quad * 4 + r;
                const int b_ = R >> 11;
                const int s_ = R & (SS - 1);
                unsigned short* orow =
                    vt + (((size_t)(b_ * HH + h) * SS) + s_) * HDD + m16;
#pragma unroll
                for (int j = 0; j < 4; j++)
                    orow[j * 16] = f2bf(acc[i][j][r] + bv[j]);
            }
        }
    } else {
        const float* scalp = (type == 0) ? q_scale : k_scale;
        const float outscale = (type == 0) ? 0.18033688011112042f : 1.0f; // 0.125*log2(e)
        unsigned short* dst = (type == 0) ? qt : kt;
        float scl[4], bv[4];
#pragma unroll
        for (int j = 0; j < 4; j++) {
            scl[j] = scalp[j * 16 + m16];
            bv[j] = bias[bn + wn + j * 16 + m16];
        }
#pragma unroll
        for (int i = 0; i < 4; i++) {
#pragma unroll
            for (int r = 0; r < 4; r++) {
                const int R = rowbase + i * 16 + quad * 4 + r;
                const int b_ = R >> 11;
                const int s_ = R & (SS - 1);
                float v0 = acc[i][0][r] + bv[0];
                float v1 = acc[i][1][r] + bv[1];
                float v2 = acc[i][2][r] + bv[2];
                float v3 = acc[i][3][r] + bv[3];
                // per-head LN (no bias): reduce across the 16 lanes of this quad
                float sm = v0 + v1 + v2 + v3;
                sm += __shfl_xor(sm, 1);
                sm += __shfl_xor(sm, 2);
                sm += __shfl_xor(sm, 4);
                sm += __shfl_xor(sm, 8);
                const float mu = sm * (1.f / 64.f);
                v0 -= mu; v1 -= mu; v2 -= mu; v3 -= mu;
                float sq = v0 * v0 + v1 * v1 + v2 * v2 + v3 * v3;
                sq += __shfl_xor(sq, 1);
                sq += __shfl_xor(sq, 2);
                sq += __shfl_xor(sq, 4);
                sq += __shfl_xor(sq, 8);
                const float rstd = rsqrtf(sq * (1.f / 64.f) + EPS);
                v0 *= rstd * scl[0];
                v1 *= rstd * scl[1];
                v2 *= rstd * scl[2];
                v3 *= rstd * scl[3];
                // RoPE: d<32: y*c - y[d+32]*s ; d>=32: y*c + y[d-32]*s
                const float c0 = ctab[s_ * 32 + m16];
                const float s0 = stab[s_ * 32 + m16];
                const float c1 = ctab[s_ * 32 + 16 + m16];
                const float s1 = stab[s_ * 32 + 16 + m16];
                const float o0 = (v0 * c0 - v2 * s0) * outscale;
                const float o1 = (v1 * c1 - v3 * s1) * outscale;
                const float o2 = (v2 * c0 + v0 * s0) * outscale;
                const float o3 = (v3 * c1 + v1 * s1) * outscale;
                unsigned short* orow =
                    dst + (((size_t)(b_ * HH + h) * SS) + s_) * HDD + m16;
                orow[0]  = f2bf(o0);
                orow[16] = f2bf(o1);
                orow[32] = f2bf(o2);
                orow[48] = f2bf(o3);
            }
        }
    }
}

// ---------------------------------------------------------------------------
// Kernel 3b: V transpose  [bh][s][d] -> [bh][d][s]  (bf16)
// ---------------------------------------------------------------------------
__global__ __launch_bounds__(256) void transpose_v(const unsigned short* __restrict__ vt,
                                                   unsigned short* __restrict__ vtT) {
    __shared__ unsigned short tile[64][72];
    const int bh = blockIdx.x >> 5;
    const int s0 = (blockIdx.x & 31) * 64;
    const int t = threadIdx.x;
    const int row = t >> 2;
    const int c0 = (t & 3) * 16;
    const unsigned short* src = vt + ((size_t)bh * SS + s0 + row) * HDD + c0;
    *(uint4*)&tile[row][c0]     = *(const uint4*)(src);
    *(uint4*)&tile[row][c0 + 8] = *(const uint4*)(src + 8);
    __syncthreads();
    unsigned short outv[16];
#pragma unroll
    for (int i = 0; i < 16; i++) outv[i] = tile[c0 + i][row];
    unsigned short* dst = vtT + ((size_t)bh * HDD + row) * SS + s0 + c0;
    *(uint4*)dst       = *(uint4*)&outv[0];
    *(uint4*)(dst + 8) = *(uint4*)&outv[8];
}

// ---------------------------------------------------------------------------
// Kernel 4: MFMA flash attention, split-K x2 LEAN (normalized bf16 partials):
// each split covers 1024 keys, computes complete-in-split l, writes
// O_i = (sum p v)/l_i as bf16 + l_i fp32; combine does the exact weighted
// average (l0*O0+l1*O1)/(l0+l1). grid 2048 = bh(32) x qtile(32) x ks(2)
// -> 8 blocks/CU by grid, 6 by LDS (24KB) -> up to 24 waves/CU (was 16).
// Body = r10's verified reg-staged + T14 prefetch + 2-barrier structure.
// XCD swizzle bijective over 2048; all blocks of a bh share one XCD.
// ---------------------------------------------------------------------------
__global__ __launch_bounds__(256, 4) void attn_mfma(const unsigned short* __restrict__ qt,
                                                    const unsigned short* __restrict__ kt,
                                                    const unsigned short* __restrict__ vtT,
                                                    unsigned short* __restrict__ Opart,
                                                    float* __restrict__ lpart) {
    __shared__ __align__(16) unsigned short KsS[64 * 64];     // 8 KB [key][d]
    __shared__ __align__(16) unsigned short VsS[64 * 64];     // 8 KB [d][key]
    __shared__ __align__(16) unsigned short PbS[4][16 * 64];  // 8 KB [q][key]

    const int bid = blockIdx.x;
    const int swz = (bid & 7) * 256 + (bid >> 3);   // bijective over 2048
    const int bh = swz >> 6;
    const int q0 = ((swz >> 1) & 31) * 64;
    const int ks = swz & 1;
    const int t = threadIdx.x;
    const int wq = t >> 6;
    const int lane = t & 63;
    const int m16 = lane & 15;
    const int quad = lane >> 4;
    const int m7 = m16 & 7;

    // loop-invariant swizzled offsets
    const int cs = quad ^ m7;
    const int koff = m16 * 64 + cs * 8;             // +g*1024, ^32 for hi chunk
    const int srow = t >> 2;
    const int sch = (t & 3) * 2;
    const int sw0 = srow * 64 + ((sch)     ^ (srow & 7)) * 8;
    const int sw1 = srow * 64 + ((sch + 1) ^ (srow & 7)) * 8;
    const int pwb = m16 * 64 + 4 * (quad & 1);      // P-write base (+chunk*8)
    const int qh = quad >> 1;

    // Q B-fragments (16 q-rows per wave), fixed all kernel
    bf16x8 qb[2];
    {
        const unsigned short* qp =
            qt + ((size_t)bh * SS + q0 + wq * 16 + m16) * HDD + quad * 8;
        qb[0] = *(const bf16x8*)qp;
        qb[1] = *(const bf16x8*)(qp + 32);
    }

    bf16x8 ones;
#pragma unroll
    for (int j = 0; j < 8; j++) ones[j] = (__bf16)1.0f;

    f32x4 O[4];
#pragma unroll
    for (int f = 0; f < 4; f++) O[f] = (f32x4){0.f, 0.f, 0.f, 0.f};
    f32x4 lacc = (f32x4){0.f, 0.f, 0.f, 0.f};

    const unsigned short* kbase = kt + (size_t)bh * SS * HDD;
    const unsigned short* vbase = vtT + (size_t)bh * HDD * SS;
    const f32x4 cinit = (f32x4){-12.f, -12.f, -12.f, -12.f};

    const int kstart = ks * (SS / 2);
    const int kend = kstart + SS / 2;

    // T14 prologue: issue first K/V tile loads into registers
    uint4 kr0, kr1, vr0, vr1;
    {
        const unsigned short* ksrc = kbase + (size_t)(kstart + srow) * HDD + sch * 8;
        const unsigned short* vsrc = vbase + (size_t)srow * SS + kstart + sch * 8;
        kr0 = *(const uint4*)ksrc;
        kr1 = *(const uint4*)(ksrc + 8);
        vr0 = *(const uint4*)vsrc;
        vr1 = *(const uint4*)(vsrc + 8);
    }

    for (int k0 = kstart; k0 < kend; k0 += 64) {
        __syncthreads();
        // reg -> LDS (loads for this tile were issued last iteration)
        *(uint4*)&KsS[sw0] = kr0;
        *(uint4*)&KsS[sw1] = kr1;
        *(uint4*)&VsS[sw0] = vr0;
        *(uint4*)&VsS[sw1] = vr1;
        __syncthreads();

        // S^T = K @ Q^T - 12 (C-init)
        f32x4 S[4];
        __builtin_amdgcn_s_setprio(1);
#pragma unroll
        for (int g = 0; g < 4; g++) {
            const bf16x8 ka0 = *(const bf16x8*)&KsS[g * 1024 + koff];
            const bf16x8 ka1 = *(const bf16x8*)&KsS[g * 1024 + (koff ^ 32)];
            f32x4 a = __builtin_amdgcn_mfma_f32_16x16x32_bf16(ka0, qb[0], cinit, 0, 0, 0);
            a = __builtin_amdgcn_mfma_f32_16x16x32_bf16(ka1, qb[1], a, 0, 0, 0);
            S[g] = a;
        }
        __builtin_amdgcn_s_setprio(0);

        // p = exp2(s); packed swizzled P store (no l adds — l via ones-MFMA)
#pragma unroll
        for (int g = 0; g < 4; g++) {
            const float p0 = exp2f(S[g][0]);
            const float p1 = exp2f(S[g][1]);
            const float p2 = exp2f(S[g][2]);
            const float p3 = exp2f(S[g][3]);
            *(uint2*)&PbS[wq][pwb + ((2 * g + qh) ^ m7) * 8] =
                pack4bf(p0, p1, p2, p3);
        }

        // T14: S-regs dead — issue NEXT tile's global loads
        if (k0 + 64 < kend) {
            const unsigned short* ksrc = kbase + (size_t)(k0 + 64 + srow) * HDD + sch * 8;
            const unsigned short* vsrc = vbase + (size_t)srow * SS + (k0 + 64) + sch * 8;
            kr0 = *(const uint4*)ksrc;
            kr1 = *(const uint4*)(ksrc + 8);
            vr0 = *(const uint4*)vsrc;
            vr1 = *(const uint4*)(vsrc + 8);
        }

        asm volatile("s_waitcnt lgkmcnt(0)" ::: "memory");

        bf16x8 pb[2];
        pb[0] = *(const bf16x8*)&PbS[wq][koff];
        pb[1] = *(const bf16x8*)&PbS[wq][koff ^ 32];

        // l += row-sums of P (ones-MFMA); O^T += V^T @ P
        __builtin_amdgcn_s_setprio(1);
        lacc = __builtin_amdgcn_mfma_f32_16x16x32_bf16(ones, pb[0], lacc, 0, 0, 0);
        lacc = __builtin_amdgcn_mfma_f32_16x16x32_bf16(ones, pb[1], lacc, 0, 0, 0);
#pragma unroll
        for (int f = 0; f < 4; f++) {
            const bf16x8 va0 = *(const bf16x8*)&VsS[f * 1024 + koff];
            const bf16x8 va1 = *(const bf16x8*)&VsS[f * 1024 + (koff ^ 32)];
            O[f] = __builtin_amdgcn_mfma_f32_16x16x32_bf16(va0, pb[0], O[f], 0, 0, 0);
            O[f] = __builtin_amdgcn_mfma_f32_16x16x32_bf16(va1, pb[1], O[f], 0, 0, 0);
        }
        __builtin_amdgcn_s_setprio(0);
    }

    // epilogue: l complete within split -> write normalized bf16 O_i + l_i.
    const int b_ = bh >> 4;
    const int h_ = bh & 15;
    {
        const float inv = 1.f / lacc[0];
        const int s_ = q0 + wq * 16 + m16;
        unsigned short* orow = Opart + (size_t)ks * ((size_t)BB * SS * DD) +
                               ((size_t)b_ * SS + s_) * DD + h_ * HDD;
#pragma unroll
        for (int f = 0; f < 4; f++)
            *(uint2*)(orow + f * 16 + quad * 4) =
                pack4bf(O[f][0] * inv, O[f][1] * inv,
                        O[f][2] * inv, O[f][3] * inv);
        if (quad == 0)
            lpart[ks * (32 * SS) + bh * SS + s_] = lacc[0];
    }
}

// ---------------------------------------------------------------------------
// Kernel 4b: combine lean split-K partials: out = (l0*O0 + l1*O1)/(l0+l1)
// ---------------------------------------------------------------------------
__global__ __launch_bounds__(256) void combine_attn(const unsigned short* __restrict__ Opart,
                                                    const float* __restrict__ lpart,
                                                    unsigned short* __restrict__ attn) {
    const int row = blockIdx.x;            // 0..4095 = b*S+s
    const int t = threadIdx.x;
    const int c = t * 4;
    const int h = t >> 4;
    const int b = row >> 11;
    const int s = row & (SS - 1);

    const size_t off = (size_t)row * DD + c;
    const uint2 u0 = *(const uint2*)(Opart + off);
    const uint2 u1 = *(const uint2*)(Opart + (size_t)BB * SS * DD + off);
    const unsigned short* p0 = (const unsigned short*)&u0;
    const unsigned short* p1 = (const unsigned short*)&u1;

    const int li = (b * HH + h) * SS + s;
    const float l0 = lpart[li];
    const float l1 = lpart[32 * SS + li];
    const float w = 1.f / (l0 + l1);
    const float w0 = l0 * w;
    const float w1 = l1 * w;

    *(uint2*)(attn + off) = pack4bf(w0 * b2f(p0[0]) + w1 * b2f(p1[0]),
                                    w0 * b2f(p0[1]) + w1 * b2f(p1[1]),
                                    w0 * b2f(p0[2]) + w1 * b2f(p1[2]),
                                    w0 * b2f(p0[3]) + w1 * b2f(p1[3]));
}

// ---------------------------------------------------------------------------
// launch
// ---------------------------------------------------------------------------
extern "C" void kernel_launch(void* const* d_in, const int* in_sizes, int n_in,
                              void* d_out, int out_size, void* d_ws, size_t ws_size,
                              hipStream_t stream) {
    const float* x        = (const float*)d_in[0];
    const float* w_qkv    = (const float*)d_in[1];
    const float* b_qkv    = (const float*)d_in[2];
    const float* w_out    = (const float*)d_in[3];
    const float* b_out    = (const float*)d_in[4];
    const float* ln_scale = (const float*)d_in[5];
    const float* ln_bias  = (const float*)d_in[6];
    const float* q_scale  = (const float*)d_in[7];
    const float* k_scale  = (const float*)d_in[8];
    float* out = (float*)d_out;

    char* ws = (char*)d_ws;
    const size_t MB = 1024 * 1024;
    // layout: [0,8) xn | [8,8.5) lpart | [9,9.25) ctab | [10,10.25) stab
    //         [16,32) Opart (bf16, 2 splits) | [64,70) wqkvT | [70,72) woutT
    //         [72,80) qt | [80,88) kt | [88,96) vt | [96,104) vtT | [104,112) attn
    unsigned short* xn    = (unsigned short*)(ws + 0);
    float*          lpart = (float*)(ws + 8 * MB);
    float*          ctab  = (float*)(ws + 9 * MB);
    float*          stab  = (float*)(ws + 10 * MB);
    unsigned short* Opart = (unsigned short*)(ws + 16 * MB);
    unsigned short* wqkvT = (unsigned short*)(ws + 64 * MB);
    unsigned short* woutT = (unsigned short*)(ws + 70 * MB);
    unsigned short* qt    = (unsigned short*)(ws + 72 * MB);
    unsigned short* kt    = (unsigned short*)(ws + 80 * MB);
    unsigned short* vt    = (unsigned short*)(ws + 88 * MB);
    unsigned short* vtT   = (unsigned short*)(ws + 96 * MB);
    unsigned short* attn  = (unsigned short*)(ws + 104 * MB);

    const int M = BB * SS;   // 4096

    cast_transpose<<<dim3(3 * DD / 32, DD / 32), 256, 0, stream>>>(w_qkv, wqkvT, DD, 3 * DD);
    cast_transpose<<<dim3(DD / 32, DD / 32), 256, 0, stream>>>(w_out, woutT, DD, DD);
    rope_tables<<<SS * 32 / 256, 256, 0, stream>>>(ctab, stab);

    ln_kernel<<<M, 256, 0, stream>>>(x, ln_scale, ln_bias, xn);

    // fused QKV GEMM + per-head LN + RoPE -> qt/kt/vt bf16 directly
    gemm_qkv_fused<<<dim3(3 * DD / 128, M / 128), 256, 0, stream>>>(
        xn, wqkvT, b_qkv, q_scale, k_scale, ctab, stab, qt, kt, vt, DD);

    transpose_v<<<BB * HH * (SS / 64), 256, 0, stream>>>(vt, vtT);

    // lean split-K x2 attention (2048 blocks -> up to 24 waves/CU)
    attn_mfma<<<dim3(2 * BB * HH * (SS / 64)), 256, 0, stream>>>(qt, kt, vtT, Opart, lpart);

    combine_attn<<<M, 256, 0, stream>>>(Opart, lpart, attn);

    // out-projection: 64x128 tile -> 512 blocks = 2/CU
    gemm_out_64<<<dim3(DD / 128, M / 64), 256, 0, stream>>>(attn, woutT, b_out, out,
                                                            M, DD, DD);
}

// Round 16
// 236.464 us; speedup vs baseline: 1.0236x; 1.0236x over previous
//
#include <hip/hip_runtime.h>
#include <math.h>

#define BB 2
#define SS 2048
#define DD 1024
#define HH 16
#define HDD 64
static constexpr float EPS = 1e-6f;

typedef __bf16 bf16x8 __attribute__((ext_vector_type(8)));
typedef __bf16 bf16x4 __attribute__((ext_vector_type(4)));
typedef float f32x4 __attribute__((ext_vector_type(4)));
typedef __attribute__((address_space(1))) const unsigned int gas_u32;
typedef __attribute__((address_space(3))) unsigned int las_u32;

__device__ __forceinline__ unsigned short f2bf(float f) {
    unsigned int u = __float_as_uint(f);
    u = (u + 0x7FFFu + ((u >> 16) & 1u)) >> 16;   // round-to-nearest-even
    return (unsigned short)u;
}

__device__ __forceinline__ uint2 pack4bf(float a, float b, float c, float d) {
    bf16x4 v;
    v[0] = (__bf16)a; v[1] = (__bf16)b; v[2] = (__bf16)c; v[3] = (__bf16)d;
    return *(uint2*)&v;
}

__device__ __forceinline__ void async_ld16(const unsigned short* g, unsigned short* l) {
    __builtin_amdgcn_global_load_lds((gas_u32*)g, (las_u32*)l, 16, 0, 0);
}

// ---------------------------------------------------------------------------
// Kernel 0: cast + transpose weights: w[K][N] fp32 -> wt[N][K] bf16
// ---------------------------------------------------------------------------
__global__ __launch_bounds__(256) void cast_transpose(const float* __restrict__ w,
                                                      unsigned short* __restrict__ wt,
                                                      int K, int N) {
    __shared__ float tile[32][36];
    const int n0 = blockIdx.x * 32;
    const int k0 = blockIdx.y * 32;
    const int t = threadIdx.x;
    const int r = t >> 3;
    const int c = (t & 7) * 4;
    *(float4*)&tile[r][c] = *(const float4*)(w + (size_t)(k0 + r) * N + n0 + c);
    __syncthreads();
    unsigned short o[4];
#pragma unroll
    for (int i = 0; i < 4; i++) o[i] = f2bf(tile[c + i][r]);
    *(uint2*)(wt + (size_t)(n0 + r) * K + k0 + c) = *(uint2*)o;
}

// ---------------------------------------------------------------------------
// Kernel 0b: RoPE tables: ctab/stab[s][i] = cos/sin(s * 10000^(-i/32))
// ---------------------------------------------------------------------------
__global__ __launch_bounds__(256) void rope_tables(float* __restrict__ ctab,
                                                   float* __restrict__ stab) {
    const int idx = blockIdx.x * 256 + threadIdx.x;   // 0..65535
    const int s = idx >> 5;
    const int i = idx & 31;
    const float ang = (float)s * exp2f(-(float)i * (13.287712379549449f / 32.f));
    ctab[idx] = cosf(ang);
    stab[idx] = sinf(ang);
}

// ---------------------------------------------------------------------------
// Kernel 1: LayerNorm rows of x [4096,1024] -> xn (bf16)
// ---------------------------------------------------------------------------
__global__ __launch_bounds__(256) void ln_kernel(const float* __restrict__ x,
                                                 const float* __restrict__ scale,
                                                 const float* __restrict__ bias,
                                                 unsigned short* __restrict__ xn) {
    __shared__ float red[4];
    const int row = blockIdx.x;
    const int t = threadIdx.x;
    const float* xr = x + (size_t)row * DD + t * 4;

    float4 v = *(const float4*)xr;
    float s = v.x + v.y + v.z + v.w;
#pragma unroll
    for (int o = 32; o; o >>= 1) s += __shfl_xor(s, o);
    if ((t & 63) == 0) red[t >> 6] = s;
    __syncthreads();
    const float mu = (red[0] + red[1] + red[2] + red[3]) * (1.f / DD);

    float4 d = {v.x - mu, v.y - mu, v.z - mu, v.w - mu};
    float sq = d.x * d.x + d.y * d.y + d.z * d.z + d.w * d.w;
#pragma unroll
    for (int o = 32; o; o >>= 1) sq += __shfl_xor(sq, o);
    __syncthreads();
    if ((t & 63) == 0) red[t >> 6] = sq;
    __syncthreads();
    const float var = (red[0] + red[1] + red[2] + red[3]) * (1.f / DD);
    const float rstd = rsqrtf(var + EPS);

    const float4 sc = *(const float4*)(scale + t * 4);
    const float4 bi = *(const float4*)(bias + t * 4);
    unsigned short o[4];
    o[0] = f2bf(d.x * rstd * sc.x + bi.x);
    o[1] = f2bf(d.y * rstd * sc.y + bi.y);
    o[2] = f2bf(d.z * rstd * sc.z + bi.z);
    o[3] = f2bf(d.w * rstd * sc.w + bi.w);
    *(uint2*)(xn + (size_t)row * DD + t * 4) = *(uint2*)o;
}

// ---------------------------------------------------------------------------
// Kernel 2: out-projection GEMM, 64x128 tile (2 blocks/CU), XCD-swizzled:
// grid (8,64) = 512 blocks; logical chunk of 64 consecutive per XCD ->
// whole 2 MB B panel L2-resident per XCD, reused 8x.
// ---------------------------------------------------------------------------
__global__ __launch_bounds__(256) void gemm_out_64(const unsigned short* __restrict__ A,
                                                   const unsigned short* __restrict__ Bt,
                                                   const float* __restrict__ bias,
                                                   float* __restrict__ C,
                                                   int M, int N, int K) {
    __shared__ __align__(16) unsigned short As[64][32];    // 4 KB
    __shared__ __align__(16) unsigned short Bs[128][32];   // 8 KB

    const int flat = blockIdx.y * 8 + blockIdx.x;   // 0..511
    const int swzb = (flat & 7) * 64 + (flat >> 3); // bijective over 512
    const int bm = (swzb >> 3) * 64;
    const int bn = (swzb & 7) * 128;
    const int t = threadIdx.x;
    const int wv = t >> 6;
    const int ln = t & 63;
    const int m16 = ln & 15;
    const int quad = ln >> 4;
    const int wn = wv * 32;

    f32x4 acc[4][2];
#pragma unroll
    for (int i = 0; i < 4; i++)
#pragma unroll
        for (int j = 0; j < 2; j++) acc[i][j] = (f32x4){0.f, 0.f, 0.f, 0.f};

    const int srow = ln >> 2;
    const int sk = (ln & 3) * 8;
    const unsigned short* aptr = A + (size_t)(bm + wv * 16 + srow) * K + sk;
    const unsigned short* bptr0 = Bt + (size_t)(bn + wv * 32 + srow) * K + sk;
    const unsigned short* bptr1 = Bt + (size_t)(bn + wv * 32 + 16 + srow) * K + sk;
    unsigned short* al = &As[wv * 16][0];
    unsigned short* bl0 = &Bs[wv * 32][0];
    unsigned short* bl1 = &Bs[wv * 32 + 16][0];

    for (int k0 = 0; k0 < K; k0 += 32) {
        __syncthreads();
        async_ld16(aptr, al);
        async_ld16(bptr0, bl0);
        async_ld16(bptr1, bl1);
        __syncthreads();

        bf16x8 af[4], bf[2];
#pragma unroll
        for (int i = 0; i < 4; i++)
            af[i] = *(const bf16x8*)&As[i * 16 + m16][quad * 8];
#pragma unroll
        for (int j = 0; j < 2; j++)
            bf[j] = *(const bf16x8*)&Bs[wn + j * 16 + m16][quad * 8];
#pragma unroll
        for (int i = 0; i < 4; i++)
#pragma unroll
            for (int j = 0; j < 2; j++)
                acc[i][j] = __builtin_amdgcn_mfma_f32_16x16x32_bf16(af[i], bf[j], acc[i][j], 0, 0, 0);

        aptr += 32;
        bptr0 += 32;
        bptr1 += 32;
    }

#pragma unroll
    for (int j = 0; j < 2; j++) {
        const int n = bn + wn + j * 16 + m16;
        const float bv = bias[n];
#pragma unroll
        for (int i = 0; i < 4; i++) {
            float* cp = C + (size_t)(bm + i * 16 + quad * 4) * N + n;
#pragma unroll
            for (int r = 0; r < 4; r++)
                cp[(size_t)r * N] = acc[i][j][r] + bv;
        }
    }
}

// ---------------------------------------------------------------------------
// Kernel 2b: fused QKV GEMM + per-head LN + RoPE epilogue -> qt/kt/vt bf16.
// XCD-swizzled: grid (24,32) = 768 blocks; 96 consecutive logical blocks per
// XCD = 4 row-panels whose A-tiles (256KB each) stay L2-resident.
// ---------------------------------------------------------------------------
__global__ __launch_bounds__(256) void gemm_qkv_fused(const unsigned short* __restrict__ A,
                                                      const unsigned short* __restrict__ Bt,
                                                      const float* __restrict__ bias,
                                                      const float* __restrict__ q_scale,
                                                      const float* __restrict__ k_scale,
                                                      const float* __restrict__ ctab,
                                                      const float* __restrict__ stab,
                                                      unsigned short* __restrict__ qt,
                                                      unsigned short* __restrict__ kt,
                                                      unsigned short* __restrict__ vt,
                                                      int K) {
    __shared__ __align__(16) unsigned short As[128][32];
    __shared__ __align__(16) unsigned short Bs[128][32];

    const int flat = blockIdx.y * 24 + blockIdx.x;   // 0..767
    const int swzb = (flat & 7) * 96 + (flat >> 3);  // bijective over 768
    const int bm = (swzb / 24) * 128;
    const int bn = (swzb % 24) * 128;
    const int t = threadIdx.x;
    const int wv = t >> 6;
    const int ln = t & 63;
    const int m16 = ln & 15;
    const int quad = ln >> 4;
    const int wm = (wv >> 1) * 64;
    const int wn = (wv & 1) * 64;

    f32x4 acc[4][4];
#pragma unroll
    for (int i = 0; i < 4; i++)
#pragma unroll
        for (int j = 0; j < 4; j++) acc[i][j] = (f32x4){0.f, 0.f, 0.f, 0.f};

    const int srow = wv * 32 + (ln >> 2);
    const int sk = (ln & 3) * 8;
    const unsigned short* aptr = A + (size_t)(bm + srow) * K + sk;
    const unsigned short* bptr = Bt + (size_t)(bn + srow) * K + sk;
    unsigned short* al0 = &As[wv * 32][0];
    unsigned short* al1 = &As[wv * 32 + 16][0];
    unsigned short* bl0 = &Bs[wv * 32][0];
    unsigned short* bl1 = &Bs[wv * 32 + 16][0];

    for (int k0 = 0; k0 < K; k0 += 32) {
        __syncthreads();
        async_ld16(aptr, al0);
        async_ld16(aptr + 16 * (size_t)K, al1);
        async_ld16(bptr, bl0);
        async_ld16(bptr + 16 * (size_t)K, bl1);
        __syncthreads();

        bf16x8 af[4], bf[4];
#pragma unroll
        for (int i = 0; i < 4; i++)
            af[i] = *(const bf16x8*)&As[wm + i * 16 + m16][quad * 8];
#pragma unroll
        for (int j = 0; j < 4; j++)
            bf[j] = *(const bf16x8*)&Bs[wn + j * 16 + m16][quad * 8];
#pragma unroll
        for (int i = 0; i < 4; i++)
#pragma unroll
            for (int j = 0; j < 4; j++)
                acc[i][j] = __builtin_amdgcn_mfma_f32_16x16x32_bf16(af[i], bf[j], acc[i][j], 0, 0, 0);

        aptr += 32;
        bptr += 32;
    }

    // -------- fused epilogue --------
    const int type = bn >> 10;                       // 0=Q, 1=K, 2=V
    const int h = ((bn & 1023) + wn) >> 6;           // this wave's head
    const int rowbase = bm + wm;

    if (type == 2) {
        // V: bias + cast + store [b,h,s,d]
        float bv[4];
#pragma unroll
        for (int j = 0; j < 4; j++) bv[j] = bias[bn + wn + j * 16 + m16];
#pragma unroll
        for (int i = 0; i < 4; i++) {
#pragma unroll
            for (int r = 0; r < 4; r++) {
                const int R = rowbase + i * 16 + quad * 4 + r;
                const int b_ = R >> 11;
                const int s_ = R & (SS - 1);
                unsigned short* orow =
                    vt + (((size_t)(b_ * HH + h) * SS) + s_) * HDD + m16;
#pragma unroll
                for (int j = 0; j < 4; j++)
                    orow[j * 16] = f2bf(acc[i][j][r] + bv[j]);
            }
        }
    } else {
        const float* scalp = (type == 0) ? q_scale : k_scale;
        const float outscale = (type == 0) ? 0.18033688011112042f : 1.0f; // 0.125*log2(e)
        unsigned short* dst = (type == 0) ? qt : kt;
        float scl[4], bv[4];
#pragma unroll
        for (int j = 0; j < 4; j++) {
            scl[j] = scalp[j * 16 + m16];
            bv[j] = bias[bn + wn + j * 16 + m16];
        }
#pragma unroll
        for (int i = 0; i < 4; i++) {
#pragma unroll
            for (int r = 0; r < 4; r++) {
                const int R = rowbase + i * 16 + quad * 4 + r;
                const int b_ = R >> 11;
                const int s_ = R & (SS - 1);
                float v0 = acc[i][0][r] + bv[0];
                float v1 = acc[i][1][r] + bv[1];
                float v2 = acc[i][2][r] + bv[2];
                float v3 = acc[i][3][r] + bv[3];
                // per-head LN (no bias): reduce across the 16 lanes of this quad
                float sm = v0 + v1 + v2 + v3;
                sm += __shfl_xor(sm, 1);
                sm += __shfl_xor(sm, 2);
                sm += __shfl_xor(sm, 4);
                sm += __shfl_xor(sm, 8);
                const float mu = sm * (1.f / 64.f);
                v0 -= mu; v1 -= mu; v2 -= mu; v3 -= mu;
                float sq = v0 * v0 + v1 * v1 + v2 * v2 + v3 * v3;
                sq += __shfl_xor(sq, 1);
                sq += __shfl_xor(sq, 2);
                sq += __shfl_xor(sq, 4);
                sq += __shfl_xor(sq, 8);
                const float rstd = rsqrtf(sq * (1.f / 64.f) + EPS);
                v0 *= rstd * scl[0];
                v1 *= rstd * scl[1];
                v2 *= rstd * scl[2];
                v3 *= rstd * scl[3];
                // RoPE: d<32: y*c - y[d+32]*s ; d>=32: y*c + y[d-32]*s
                const float c0 = ctab[s_ * 32 + m16];
                const float s0 = stab[s_ * 32 + m16];
                const float c1 = ctab[s_ * 32 + 16 + m16];
                const float s1 = stab[s_ * 32 + 16 + m16];
                const float o0 = (v0 * c0 - v2 * s0) * outscale;
                const float o1 = (v1 * c1 - v3 * s1) * outscale;
                const float o2 = (v2 * c0 + v0 * s0) * outscale;
                const float o3 = (v3 * c1 + v1 * s1) * outscale;
                unsigned short* orow =
                    dst + (((size_t)(b_ * HH + h) * SS) + s_) * HDD + m16;
                orow[0]  = f2bf(o0);
                orow[16] = f2bf(o1);
                orow[32] = f2bf(o2);
                orow[48] = f2bf(o3);
            }
        }
    }
}

// ---------------------------------------------------------------------------
// Kernel 3b: V transpose  [bh][s][d] -> [bh][d][s]  (bf16)
// ---------------------------------------------------------------------------
__global__ __launch_bounds__(256) void transpose_v(const unsigned short* __restrict__ vt,
                                                   unsigned short* __restrict__ vtT) {
    __shared__ unsigned short tile[64][72];
    const int bh = blockIdx.x >> 5;
    const int s0 = (blockIdx.x & 31) * 64;
    const int t = threadIdx.x;
    const int row = t >> 2;
    const int c0 = (t & 3) * 16;
    const unsigned short* src = vt + ((size_t)bh * SS + s0 + row) * HDD + c0;
    *(uint4*)&tile[row][c0]     = *(const uint4*)(src);
    *(uint4*)&tile[row][c0 + 8] = *(const uint4*)(src + 8);
    __syncthreads();
    unsigned short outv[16];
#pragma unroll
    for (int i = 0; i < 16; i++) outv[i] = tile[c0 + i][row];
    unsigned short* dst = vtT + ((size_t)bh * HDD + row) * SS + s0 + c0;
    *(uint4*)dst       = *(uint4*)&outv[0];
    *(uint4*)(dst + 8) = *(uint4*)&outv[8];
}

// ---------------------------------------------------------------------------
// Kernel 4: MFMA flash attention, single-pass, split-Q 64-row tiles
// (r10-verified body: 66.6 us). grid 1024 = bh*32 + qtile(64), XCD-swizzled
// (bijective). 4 waves, 16 q/wave. S^T = K@Q^T, C-init=-12; p=exp2(S);
// l via ones-MFMA; O^T = V^T@P; T14 reg-prefetch; T5 setprio; l complete
// in-register -> normalize in-kernel, write bf16 attn directly.
// ---------------------------------------------------------------------------
__global__ __launch_bounds__(256, 4) void attn_mfma(const unsigned short* __restrict__ qt,
                                                    const unsigned short* __restrict__ kt,
                                                    const unsigned short* __restrict__ vtT,
                                                    unsigned short* __restrict__ attn) {
    __shared__ __align__(16) unsigned short KsS[64 * 64];     // 8 KB [key][d]
    __shared__ __align__(16) unsigned short VsS[64 * 64];     // 8 KB [d][key]
    __shared__ __align__(16) unsigned short PbS[4][16 * 64];  // 8 KB [q][key]

    const int bid = blockIdx.x;
    const int swz = (bid & 7) * 128 + (bid >> 3);   // bijective over 1024
    const int bh = swz >> 5;
    const int q0 = (swz & 31) * 64;
    const int t = threadIdx.x;
    const int wq = t >> 6;
    const int lane = t & 63;
    const int m16 = lane & 15;
    const int quad = lane >> 4;
    const int m7 = m16 & 7;

    // loop-invariant swizzled offsets
    const int cs = quad ^ m7;
    const int koff = m16 * 64 + cs * 8;             // +g*1024, ^32 for hi chunk
    const int srow = t >> 2;
    const int sch = (t & 3) * 2;
    const int sw0 = srow * 64 + ((sch)     ^ (srow & 7)) * 8;
    const int sw1 = srow * 64 + ((sch + 1) ^ (srow & 7)) * 8;
    const int pwb = m16 * 64 + 4 * (quad & 1);      // P-write base (+chunk*8)
    const int qh = quad >> 1;

    // Q B-fragments (16 q-rows per wave), fixed all kernel
    bf16x8 qb[2];
    {
        const unsigned short* qp =
            qt + ((size_t)bh * SS + q0 + wq * 16 + m16) * HDD + quad * 8;
        qb[0] = *(const bf16x8*)qp;
        qb[1] = *(const bf16x8*)(qp + 32);
    }

    bf16x8 ones;
#pragma unroll
    for (int j = 0; j < 8; j++) ones[j] = (__bf16)1.0f;

    f32x4 O[4];
#pragma unroll
    for (int f = 0; f < 4; f++) O[f] = (f32x4){0.f, 0.f, 0.f, 0.f};
    f32x4 lacc = (f32x4){0.f, 0.f, 0.f, 0.f};

    const unsigned short* kbase = kt + (size_t)bh * SS * HDD;
    const unsigned short* vbase = vtT + (size_t)bh * HDD * SS;
    const f32x4 cinit = (f32x4){-12.f, -12.f, -12.f, -12.f};

    // T14 prologue: issue first K/V tile loads into registers
    uint4 kr0, kr1, vr0, vr1;
    {
        const unsigned short* ksrc = kbase + (size_t)srow * HDD + sch * 8;
        const unsigned short* vsrc = vbase + (size_t)srow * SS + sch * 8;
        kr0 = *(const uint4*)ksrc;
        kr1 = *(const uint4*)(ksrc + 8);
        vr0 = *(const uint4*)vsrc;
        vr1 = *(const uint4*)(vsrc + 8);
    }

    for (int k0 = 0; k0 < SS; k0 += 64) {
        __syncthreads();
        // reg -> LDS (loads for this tile were issued last iteration)
        *(uint4*)&KsS[sw0] = kr0;
        *(uint4*)&KsS[sw1] = kr1;
        *(uint4*)&VsS[sw0] = vr0;
        *(uint4*)&VsS[sw1] = vr1;
        __syncthreads();

        // S^T = K @ Q^T - 12 (C-init)
        f32x4 S[4];
        __builtin_amdgcn_s_setprio(1);
#pragma unroll
        for (int g = 0; g < 4; g++) {
            const bf16x8 ka0 = *(const bf16x8*)&KsS[g * 1024 + koff];
            const bf16x8 ka1 = *(const bf16x8*)&KsS[g * 1024 + (koff ^ 32)];
            f32x4 a = __builtin_amdgcn_mfma_f32_16x16x32_bf16(ka0, qb[0], cinit, 0, 0, 0);
            a = __builtin_amdgcn_mfma_f32_16x16x32_bf16(ka1, qb[1], a, 0, 0, 0);
            S[g] = a;
        }
        __builtin_amdgcn_s_setprio(0);

        // p = exp2(s); packed swizzled P store (per-wave buffer)
#pragma unroll
        for (int g = 0; g < 4; g++) {
            const float p0 = exp2f(S[g][0]);
            const float p1 = exp2f(S[g][1]);
            const float p2 = exp2f(S[g][2]);
            const float p3 = exp2f(S[g][3]);
            *(uint2*)&PbS[wq][pwb + ((2 * g + qh) ^ m7) * 8] =
                pack4bf(p0, p1, p2, p3);
        }

        // T14: S-regs dead — issue NEXT tile's global loads
        if (k0 + 64 < SS) {
            const unsigned short* ksrc = kbase + (size_t)(k0 + 64 + srow) * HDD + sch * 8;
            const unsigned short* vsrc = vbase + (size_t)srow * SS + (k0 + 64) + sch * 8;
            kr0 = *(const uint4*)ksrc;
            kr1 = *(const uint4*)(ksrc + 8);
            vr0 = *(const uint4*)vsrc;
            vr1 = *(const uint4*)(vsrc + 8);
        }

        asm volatile("s_waitcnt lgkmcnt(0)" ::: "memory");

        bf16x8 pb[2];
        pb[0] = *(const bf16x8*)&PbS[wq][koff];
        pb[1] = *(const bf16x8*)&PbS[wq][koff ^ 32];

        // l += row-sums of P (ones-MFMA); O^T += V^T @ P
        __builtin_amdgcn_s_setprio(1);
        lacc = __builtin_amdgcn_mfma_f32_16x16x32_bf16(ones, pb[0], lacc, 0, 0, 0);
        lacc = __builtin_amdgcn_mfma_f32_16x16x32_bf16(ones, pb[1], lacc, 0, 0, 0);
#pragma unroll
        for (int f = 0; f < 4; f++) {
            const bf16x8 va0 = *(const bf16x8*)&VsS[f * 1024 + koff];
            const bf16x8 va1 = *(const bf16x8*)&VsS[f * 1024 + (koff ^ 32)];
            O[f] = __builtin_amdgcn_mfma_f32_16x16x32_bf16(va0, pb[0], O[f], 0, 0, 0);
            O[f] = __builtin_amdgcn_mfma_f32_16x16x32_bf16(va1, pb[1], O[f], 0, 0, 0);
        }
        __builtin_amdgcn_s_setprio(0);
    }

    // epilogue: l complete -> normalize, write bf16 attn [b][s][h*64+d].
    const int b_ = bh >> 4;
    const int h_ = bh & 15;
    {
        const float inv = 1.f / lacc[0];
        const int s_ = q0 + wq * 16 + m16;
        unsigned short* orow = attn + ((size_t)b_ * SS + s_) * DD + h_ * HDD;
#pragma unroll
        for (int f = 0; f < 4; f++)
            *(uint2*)(orow + f * 16 + quad * 4) =
                pack4bf(O[f][0] * inv, O[f][1] * inv,
                        O[f][2] * inv, O[f][3] * inv);
    }
}

// ---------------------------------------------------------------------------
// launch
// ---------------------------------------------------------------------------
extern "C" void kernel_launch(void* const* d_in, const int* in_sizes, int n_in,
                              void* d_out, int out_size, void* d_ws, size_t ws_size,
                              hipStream_t stream) {
    const float* x        = (const float*)d_in[0];
    const float* w_qkv    = (const float*)d_in[1];
    const float* b_qkv    = (const float*)d_in[2];
    const float* w_out    = (const float*)d_in[3];
    const float* b_out    = (const float*)d_in[4];
    const float* ln_scale = (const float*)d_in[5];
    const float* ln_bias  = (const float*)d_in[6];
    const float* q_scale  = (const float*)d_in[7];
    const float* k_scale  = (const float*)d_in[8];
    float* out = (float*)d_out;

    char* ws = (char*)d_ws;
    const size_t MB = 1024 * 1024;
    unsigned short* xn    = (unsigned short*)(ws + 0);
    float*          ctab  = (float*)(ws + 9 * MB);
    float*          stab  = (float*)(ws + 10 * MB);
    unsigned short* wqkvT = (unsigned short*)(ws + 64 * MB);
    unsigned short* woutT = (unsigned short*)(ws + 70 * MB);
    unsigned short* qt    = (unsigned short*)(ws + 72 * MB);
    unsigned short* kt    = (unsigned short*)(ws + 80 * MB);
    unsigned short* vt    = (unsigned short*)(ws + 88 * MB);
    unsigned short* vtT   = (unsigned short*)(ws + 96 * MB);
    unsigned short* attn  = (unsigned short*)(ws + 104 * MB);

    const int M = BB * SS;   // 4096

    cast_transpose<<<dim3(3 * DD / 32, DD / 32), 256, 0, stream>>>(w_qkv, wqkvT, DD, 3 * DD);
    cast_transpose<<<dim3(DD / 32, DD / 32), 256, 0, stream>>>(w_out, woutT, DD, DD);
    rope_tables<<<SS * 32 / 256, 256, 0, stream>>>(ctab, stab);

    ln_kernel<<<M, 256, 0, stream>>>(x, ln_scale, ln_bias, xn);

    // fused QKV GEMM + per-head LN + RoPE -> qt/kt/vt bf16 directly
    gemm_qkv_fused<<<dim3(3 * DD / 128, M / 128), 256, 0, stream>>>(
        xn, wqkvT, b_qkv, q_scale, k_scale, ctab, stab, qt, kt, vt, DD);

    transpose_v<<<BB * HH * (SS / 64), 256, 0, stream>>>(vt, vtT);

    // single-pass attention, split-Q 64 (1024 blocks), bf16 output direct
    attn_mfma<<<dim3(BB * HH * (SS / 64)), 256, 0, stream>>>(qt, kt, vtT, attn);

    // out-projection: 64x128 tile -> 512 blocks = 2/CU, XCD-swizzled
    gemm_out_64<<<dim3(DD / 128, M / 64), 256, 0, stream>>>(attn, woutT, b_out, out,
                                                            M, DD, DD);
}

// Round 17
// 230.378 us; speedup vs baseline: 1.0506x; 1.0264x over previous
//
#include <hip/hip_runtime.h>
#include <math.h>

#define BB 2
#define SS 2048
#define DD 1024
#define HH 16
#define HDD 64
static constexpr float EPS = 1e-6f;

typedef __bf16 bf16x8 __attribute__((ext_vector_type(8)));
typedef __bf16 bf16x4 __attribute__((ext_vector_type(4)));
typedef float f32x4 __attribute__((ext_vector_type(4)));
typedef __attribute__((address_space(1))) const unsigned int gas_u32;
typedef __attribute__((address_space(3))) unsigned int las_u32;

__device__ __forceinline__ unsigned short f2bf(float f) {
    unsigned int u = __float_as_uint(f);
    u = (u + 0x7FFFu + ((u >> 16) & 1u)) >> 16;   // round-to-nearest-even
    return (unsigned short)u;
}

__device__ __forceinline__ uint2 pack4bf(float a, float b, float c, float d) {
    bf16x4 v;
    v[0] = (__bf16)a; v[1] = (__bf16)b; v[2] = (__bf16)c; v[3] = (__bf16)d;
    return *(uint2*)&v;
}

__device__ __forceinline__ void async_ld16(const unsigned short* g, unsigned short* l) {
    __builtin_amdgcn_global_load_lds((gas_u32*)g, (las_u32*)l, 16, 0, 0);
}

// ---------------------------------------------------------------------------
// Kernel 0 (fused prep): one flat grid covering 4 independent sub-kernels,
// each body identical to its verified standalone version:
//   [0,3072)    cast+transpose w_qkv [1024][3072] -> wqkvT [3072][1024]
//   [3072,4096) cast+transpose w_out [1024][1024] -> woutT
//   [4096,4352) RoPE tables
//   [4352,8448) LayerNorm rows of x -> xn (bf16)
// Saves 3 kernel launches vs separate dispatches.
// ---------------------------------------------------------------------------
__global__ __launch_bounds__(256) void prep_fused(const float* __restrict__ w_qkv,
                                                  const float* __restrict__ w_out,
                                                  const float* __restrict__ x,
                                                  const float* __restrict__ ln_scale,
                                                  const float* __restrict__ ln_bias,
                                                  unsigned short* __restrict__ wqkvT,
                                                  unsigned short* __restrict__ woutT,
                                                  float* __restrict__ ctab,
                                                  float* __restrict__ stab,
                                                  unsigned short* __restrict__ xn) {
    __shared__ float tile[32][36];
    __shared__ float red[4];
    const int bid = blockIdx.x;
    const int t = threadIdx.x;

    if (bid < 4096) {
        // ---- cast + transpose (w_qkv tiles first, then w_out tiles) ----
        const float* w;
        unsigned short* wt;
        int n0, k0, N;
        if (bid < 3072) {
            w = w_qkv; wt = wqkvT; N = 3 * DD;
            n0 = (bid % 96) * 32;
            k0 = (bid / 96) * 32;
        } else {
            const int idx = bid - 3072;
            w = w_out; wt = woutT; N = DD;
            n0 = (idx % 32) * 32;
            k0 = (idx / 32) * 32;
        }
        const int r = t >> 3;
        const int c = (t & 7) * 4;
        *(float4*)&tile[r][c] = *(const float4*)(w + (size_t)(k0 + r) * N + n0 + c);
        __syncthreads();
        unsigned short o[4];
#pragma unroll
        for (int i = 0; i < 4; i++) o[i] = f2bf(tile[c + i][r]);
        *(uint2*)(wt + (size_t)(n0 + r) * DD + k0 + c) = *(uint2*)o;
    } else if (bid < 4352) {
        // ---- RoPE tables ----
        const int idx = (bid - 4096) * 256 + t;   // 0..65535
        const int s = idx >> 5;
        const int i = idx & 31;
        const float ang = (float)s * exp2f(-(float)i * (13.287712379549449f / 32.f));
        ctab[idx] = cosf(ang);
        stab[idx] = sinf(ang);
    } else {
        // ---- LayerNorm row ----
        const int row = bid - 4352;               // 0..4095
        const float* xr = x + (size_t)row * DD + t * 4;

        float4 v = *(const float4*)xr;
        float s = v.x + v.y + v.z + v.w;
#pragma unroll
        for (int o = 32; o; o >>= 1) s += __shfl_xor(s, o);
        if ((t & 63) == 0) red[t >> 6] = s;
        __syncthreads();
        const float mu = (red[0] + red[1] + red[2] + red[3]) * (1.f / DD);

        float4 d = {v.x - mu, v.y - mu, v.z - mu, v.w - mu};
        float sq = d.x * d.x + d.y * d.y + d.z * d.z + d.w * d.w;
#pragma unroll
        for (int o = 32; o; o >>= 1) sq += __shfl_xor(sq, o);
        __syncthreads();
        if ((t & 63) == 0) red[t >> 6] = sq;
        __syncthreads();
        const float var = (red[0] + red[1] + red[2] + red[3]) * (1.f / DD);
        const float rstd = rsqrtf(var + EPS);

        const float4 sc = *(const float4*)(ln_scale + t * 4);
        const float4 bi = *(const float4*)(ln_bias + t * 4);
        unsigned short o[4];
        o[0] = f2bf(d.x * rstd * sc.x + bi.x);
        o[1] = f2bf(d.y * rstd * sc.y + bi.y);
        o[2] = f2bf(d.z * rstd * sc.z + bi.z);
        o[3] = f2bf(d.w * rstd * sc.w + bi.w);
        *(uint2*)(xn + (size_t)row * DD + t * 4) = *(uint2*)o;
    }
}

// ---------------------------------------------------------------------------
// Kernel 2: out-projection GEMM, 64x128 tile (2 blocks/CU), XCD-swizzled.
// ---------------------------------------------------------------------------
__global__ __launch_bounds__(256) void gemm_out_64(const unsigned short* __restrict__ A,
                                                   const unsigned short* __restrict__ Bt,
                                                   const float* __restrict__ bias,
                                                   float* __restrict__ C,
                                                   int M, int N, int K) {
    __shared__ __align__(16) unsigned short As[64][32];    // 4 KB
    __shared__ __align__(16) unsigned short Bs[128][32];   // 8 KB

    const int flat = blockIdx.y * 8 + blockIdx.x;   // 0..511
    const int swzb = (flat & 7) * 64 + (flat >> 3); // bijective over 512
    const int bm = (swzb >> 3) * 64;
    const int bn = (swzb & 7) * 128;
    const int t = threadIdx.x;
    const int wv = t >> 6;
    const int ln = t & 63;
    const int m16 = ln & 15;
    const int quad = ln >> 4;
    const int wn = wv * 32;

    f32x4 acc[4][2];
#pragma unroll
    for (int i = 0; i < 4; i++)
#pragma unroll
        for (int j = 0; j < 2; j++) acc[i][j] = (f32x4){0.f, 0.f, 0.f, 0.f};

    const int srow = ln >> 2;
    const int sk = (ln & 3) * 8;
    const unsigned short* aptr = A + (size_t)(bm + wv * 16 + srow) * K + sk;
    const unsigned short* bptr0 = Bt + (size_t)(bn + wv * 32 + srow) * K + sk;
    const unsigned short* bptr1 = Bt + (size_t)(bn + wv * 32 + 16 + srow) * K + sk;
    unsigned short* al = &As[wv * 16][0];
    unsigned short* bl0 = &Bs[wv * 32][0];
    unsigned short* bl1 = &Bs[wv * 32 + 16][0];

    for (int k0 = 0; k0 < K; k0 += 32) {
        __syncthreads();
        async_ld16(aptr, al);
        async_ld16(bptr0, bl0);
        async_ld16(bptr1, bl1);
        __syncthreads();

        bf16x8 af[4], bf[2];
#pragma unroll
        for (int i = 0; i < 4; i++)
            af[i] = *(const bf16x8*)&As[i * 16 + m16][quad * 8];
#pragma unroll
        for (int j = 0; j < 2; j++)
            bf[j] = *(const bf16x8*)&Bs[wn + j * 16 + m16][quad * 8];
#pragma unroll
        for (int i = 0; i < 4; i++)
#pragma unroll
            for (int j = 0; j < 2; j++)
                acc[i][j] = __builtin_amdgcn_mfma_f32_16x16x32_bf16(af[i], bf[j], acc[i][j], 0, 0, 0);

        aptr += 32;
        bptr0 += 32;
        bptr1 += 32;
    }

#pragma unroll
    for (int j = 0; j < 2; j++) {
        const int n = bn + wn + j * 16 + m16;
        const float bv = bias[n];
#pragma unroll
        for (int i = 0; i < 4; i++) {
            float* cp = C + (size_t)(bm + i * 16 + quad * 4) * N + n;
#pragma unroll
            for (int r = 0; r < 4; r++)
                cp[(size_t)r * N] = acc[i][j][r] + bv;
        }
    }
}

// ---------------------------------------------------------------------------
// Kernel 2b: fused QKV GEMM + per-head LN + RoPE epilogue -> qt/kt/vt bf16.
// XCD-swizzled (bijective over 768).
// ---------------------------------------------------------------------------
__global__ __launch_bounds__(256) void gemm_qkv_fused(const unsigned short* __restrict__ A,
                                                      const unsigned short* __restrict__ Bt,
                                                      const float* __restrict__ bias,
                                                      const float* __restrict__ q_scale,
                                                      const float* __restrict__ k_scale,
                                                      const float* __restrict__ ctab,
                                                      const float* __restrict__ stab,
                                                      unsigned short* __restrict__ qt,
                                                      unsigned short* __restrict__ kt,
                                                      unsigned short* __restrict__ vt,
                                                      int K) {
    __shared__ __align__(16) unsigned short As[128][32];
    __shared__ __align__(16) unsigned short Bs[128][32];

    const int flat = blockIdx.y * 24 + blockIdx.x;   // 0..767
    const int swzb = (flat & 7) * 96 + (flat >> 3);  // bijective over 768
    const int bm = (swzb / 24) * 128;
    const int bn = (swzb % 24) * 128;
    const int t = threadIdx.x;
    const int wv = t >> 6;
    const int ln = t & 63;
    const int m16 = ln & 15;
    const int quad = ln >> 4;
    const int wm = (wv >> 1) * 64;
    const int wn = (wv & 1) * 64;

    f32x4 acc[4][4];
#pragma unroll
    for (int i = 0; i < 4; i++)
#pragma unroll
        for (int j = 0; j < 4; j++) acc[i][j] = (f32x4){0.f, 0.f, 0.f, 0.f};

    const int srow = wv * 32 + (ln >> 2);
    const int sk = (ln & 3) * 8;
    const unsigned short* aptr = A + (size_t)(bm + srow) * K + sk;
    const unsigned short* bptr = Bt + (size_t)(bn + srow) * K + sk;
    unsigned short* al0 = &As[wv * 32][0];
    unsigned short* al1 = &As[wv * 32 + 16][0];
    unsigned short* bl0 = &Bs[wv * 32][0];
    unsigned short* bl1 = &Bs[wv * 32 + 16][0];

    for (int k0 = 0; k0 < K; k0 += 32) {
        __syncthreads();
        async_ld16(aptr, al0);
        async_ld16(aptr + 16 * (size_t)K, al1);
        async_ld16(bptr, bl0);
        async_ld16(bptr + 16 * (size_t)K, bl1);
        __syncthreads();

        bf16x8 af[4], bf[4];
#pragma unroll
        for (int i = 0; i < 4; i++)
            af[i] = *(const bf16x8*)&As[wm + i * 16 + m16][quad * 8];
#pragma unroll
        for (int j = 0; j < 4; j++)
            bf[j] = *(const bf16x8*)&Bs[wn + j * 16 + m16][quad * 8];
#pragma unroll
        for (int i = 0; i < 4; i++)
#pragma unroll
            for (int j = 0; j < 4; j++)
                acc[i][j] = __builtin_amdgcn_mfma_f32_16x16x32_bf16(af[i], bf[j], acc[i][j], 0, 0, 0);

        aptr += 32;
        bptr += 32;
    }

    // -------- fused epilogue --------
    const int type = bn >> 10;                       // 0=Q, 1=K, 2=V
    const int h = ((bn & 1023) + wn) >> 6;           // this wave's head
    const int rowbase = bm + wm;

    if (type == 2) {
        // V: bias + cast + store [b,h,s,d]
        float bv[4];
#pragma unroll
        for (int j = 0; j < 4; j++) bv[j] = bias[bn + wn + j * 16 + m16];
#pragma unroll
        for (int i = 0; i < 4; i++) {
#pragma unroll
            for (int r = 0; r < 4; r++) {
                const int R = rowbase + i * 16 + quad * 4 + r;
                const int b_ = R >> 11;
                const int s_ = R & (SS - 1);
                unsigned short* orow =
                    vt + (((size_t)(b_ * HH + h) * SS) + s_) * HDD + m16;
#pragma unroll
                for (int j = 0; j < 4; j++)
                    orow[j * 16] = f2bf(acc[i][j][r] + bv[j]);
            }
        }
    } else {
        const float* scalp = (type == 0) ? q_scale : k_scale;
        const float outscale = (type == 0) ? 0.18033688011112042f : 1.0f; // 0.125*log2(e)
        unsigned short* dst = (type == 0) ? qt : kt;
        float scl[4], bv[4];
#pragma unroll
        for (int j = 0; j < 4; j++) {
            scl[j] = scalp[j * 16 + m16];
            bv[j] = bias[bn + wn + j * 16 + m16];
        }
#pragma unroll
        for (int i = 0; i < 4; i++) {
#pragma unroll
            for (int r = 0; r < 4; r++) {
                const int R = rowbase + i * 16 + quad * 4 + r;
                const int b_ = R >> 11;
                const int s_ = R & (SS - 1);
                float v0 = acc[i][0][r] + bv[0];
                float v1 = acc[i][1][r] + bv[1];
                float v2 = acc[i][2][r] + bv[2];
                float v3 = acc[i][3][r] + bv[3];
                // per-head LN (no bias): reduce across the 16 lanes of this quad
                float sm = v0 + v1 + v2 + v3;
                sm += __shfl_xor(sm, 1);
                sm += __shfl_xor(sm, 2);
                sm += __shfl_xor(sm, 4);
                sm += __shfl_xor(sm, 8);
                const float mu = sm * (1.f / 64.f);
                v0 -= mu; v1 -= mu; v2 -= mu; v3 -= mu;
                float sq = v0 * v0 + v1 * v1 + v2 * v2 + v3 * v3;
                sq += __shfl_xor(sq, 1);
                sq += __shfl_xor(sq, 2);
                sq += __shfl_xor(sq, 4);
                sq += __shfl_xor(sq, 8);
                const float rstd = rsqrtf(sq * (1.f / 64.f) + EPS);
                v0 *= rstd * scl[0];
                v1 *= rstd * scl[1];
                v2 *= rstd * scl[2];
                v3 *= rstd * scl[3];
                // RoPE: d<32: y*c - y[d+32]*s ; d>=32: y*c + y[d-32]*s
                const float c0 = ctab[s_ * 32 + m16];
                const float s0 = stab[s_ * 32 + m16];
                const float c1 = ctab[s_ * 32 + 16 + m16];
                const float s1 = stab[s_ * 32 + 16 + m16];
                const float o0 = (v0 * c0 - v2 * s0) * outscale;
                const float o1 = (v1 * c1 - v3 * s1) * outscale;
                const float o2 = (v2 * c0 + v0 * s0) * outscale;
                const float o3 = (v3 * c1 + v1 * s1) * outscale;
                unsigned short* orow =
                    dst + (((size_t)(b_ * HH + h) * SS) + s_) * HDD + m16;
                orow[0]  = f2bf(o0);
                orow[16] = f2bf(o1);
                orow[32] = f2bf(o2);
                orow[48] = f2bf(o3);
            }
        }
    }
}

// ---------------------------------------------------------------------------
// Kernel 3b: V transpose  [bh][s][d] -> [bh][d][s]  (bf16)
// ---------------------------------------------------------------------------
__global__ __launch_bounds__(256) void transpose_v(const unsigned short* __restrict__ vt,
                                                   unsigned short* __restrict__ vtT) {
    __shared__ unsigned short tile[64][72];
    const int bh = blockIdx.x >> 5;
    const int s0 = (blockIdx.x & 31) * 64;
    const int t = threadIdx.x;
    const int row = t >> 2;
    const int c0 = (t & 3) * 16;
    const unsigned short* src = vt + ((size_t)bh * SS + s0 + row) * HDD + c0;
    *(uint4*)&tile[row][c0]     = *(const uint4*)(src);
    *(uint4*)&tile[row][c0 + 8] = *(const uint4*)(src + 8);
    __syncthreads();
    unsigned short outv[16];
#pragma unroll
    for (int i = 0; i < 16; i++) outv[i] = tile[c0 + i][row];
    unsigned short* dst = vtT + ((size_t)bh * HDD + row) * SS + s0 + c0;
    *(uint4*)dst       = *(uint4*)&outv[0];
    *(uint4*)(dst + 8) = *(uint4*)&outv[8];
}

// ---------------------------------------------------------------------------
// Kernel 4: MFMA flash attention, single-pass, split-Q 64-row tiles
// (r10-verified body: 66.6 us). grid 1024 = bh*32 + qtile(64), XCD-swizzled.
// ---------------------------------------------------------------------------
__global__ __launch_bounds__(256, 4) void attn_mfma(const unsigned short* __restrict__ qt,
                                                    const unsigned short* __restrict__ kt,
                                                    const unsigned short* __restrict__ vtT,
                                                    unsigned short* __restrict__ attn) {
    __shared__ __align__(16) unsigned short KsS[64 * 64];     // 8 KB [key][d]
    __shared__ __align__(16) unsigned short VsS[64 * 64];     // 8 KB [d][key]
    __shared__ __align__(16) unsigned short PbS[4][16 * 64];  // 8 KB [q][key]

    const int bid = blockIdx.x;
    const int swz = (bid & 7) * 128 + (bid >> 3);   // bijective over 1024
    const int bh = swz >> 5;
    const int q0 = (swz & 31) * 64;
    const int t = threadIdx.x;
    const int wq = t >> 6;
    const int lane = t & 63;
    const int m16 = lane & 15;
    const int quad = lane >> 4;
    const int m7 = m16 & 7;

    // loop-invariant swizzled offsets
    const int cs = quad ^ m7;
    const int koff = m16 * 64 + cs * 8;             // +g*1024, ^32 for hi chunk
    const int srow = t >> 2;
    const int sch = (t & 3) * 2;
    const int sw0 = srow * 64 + ((sch)     ^ (srow & 7)) * 8;
    const int sw1 = srow * 64 + ((sch + 1) ^ (srow & 7)) * 8;
    const int pwb = m16 * 64 + 4 * (quad & 1);      // P-write base (+chunk*8)
    const int qh = quad >> 1;

    // Q B-fragments (16 q-rows per wave), fixed all kernel
    bf16x8 qb[2];
    {
        const unsigned short* qp =
            qt + ((size_t)bh * SS + q0 + wq * 16 + m16) * HDD + quad * 8;
        qb[0] = *(const bf16x8*)qp;
        qb[1] = *(const bf16x8*)(qp + 32);
    }

    bf16x8 ones;
#pragma unroll
    for (int j = 0; j < 8; j++) ones[j] = (__bf16)1.0f;

    f32x4 O[4];
#pragma unroll
    for (int f = 0; f < 4; f++) O[f] = (f32x4){0.f, 0.f, 0.f, 0.f};
    f32x4 lacc = (f32x4){0.f, 0.f, 0.f, 0.f};

    const unsigned short* kbase = kt + (size_t)bh * SS * HDD;
    const unsigned short* vbase = vtT + (size_t)bh * HDD * SS;
    const f32x4 cinit = (f32x4){-12.f, -12.f, -12.f, -12.f};

    // T14 prologue: issue first K/V tile loads into registers
    uint4 kr0, kr1, vr0, vr1;
    {
        const unsigned short* ksrc = kbase + (size_t)srow * HDD + sch * 8;
        const unsigned short* vsrc = vbase + (size_t)srow * SS + sch * 8;
        kr0 = *(const uint4*)ksrc;
        kr1 = *(const uint4*)(ksrc + 8);
        vr0 = *(const uint4*)vsrc;
        vr1 = *(const uint4*)(vsrc + 8);
    }

    for (int k0 = 0; k0 < SS; k0 += 64) {
        __syncthreads();
        // reg -> LDS (loads for this tile were issued last iteration)
        *(uint4*)&KsS[sw0] = kr0;
        *(uint4*)&KsS[sw1] = kr1;
        *(uint4*)&VsS[sw0] = vr0;
        *(uint4*)&VsS[sw1] = vr1;
        __syncthreads();

        // S^T = K @ Q^T - 12 (C-init)
        f32x4 S[4];
        __builtin_amdgcn_s_setprio(1);
#pragma unroll
        for (int g = 0; g < 4; g++) {
            const bf16x8 ka0 = *(const bf16x8*)&KsS[g * 1024 + koff];
            const bf16x8 ka1 = *(const bf16x8*)&KsS[g * 1024 + (koff ^ 32)];
            f32x4 a = __builtin_amdgcn_mfma_f32_16x16x32_bf16(ka0, qb[0], cinit, 0, 0, 0);
            a = __builtin_amdgcn_mfma_f32_16x16x32_bf16(ka1, qb[1], a, 0, 0, 0);
            S[g] = a;
        }
        __builtin_amdgcn_s_setprio(0);

        // p = exp2(s); packed swizzled P store (per-wave buffer)
#pragma unroll
        for (int g = 0; g < 4; g++) {
            const float p0 = exp2f(S[g][0]);
            const float p1 = exp2f(S[g][1]);
            const float p2 = exp2f(S[g][2]);
            const float p3 = exp2f(S[g][3]);
            *(uint2*)&PbS[wq][pwb + ((2 * g + qh) ^ m7) * 8] =
                pack4bf(p0, p1, p2, p3);
        }

        // T14: S-regs dead — issue NEXT tile's global loads
        if (k0 + 64 < SS) {
            const unsigned short* ksrc = kbase + (size_t)(k0 + 64 + srow) * HDD + sch * 8;
            const unsigned short* vsrc = vbase + (size_t)srow * SS + (k0 + 64) + sch * 8;
            kr0 = *(const uint4*)ksrc;
            kr1 = *(const uint4*)(ksrc + 8);
            vr0 = *(const uint4*)vsrc;
            vr1 = *(const uint4*)(vsrc + 8);
        }

        asm volatile("s_waitcnt lgkmcnt(0)" ::: "memory");

        bf16x8 pb[2];
        pb[0] = *(const bf16x8*)&PbS[wq][koff];
        pb[1] = *(const bf16x8*)&PbS[wq][koff ^ 32];

        // l += row-sums of P (ones-MFMA); O^T += V^T @ P
        __builtin_amdgcn_s_setprio(1);
        lacc = __builtin_amdgcn_mfma_f32_16x16x32_bf16(ones, pb[0], lacc, 0, 0, 0);
        lacc = __builtin_amdgcn_mfma_f32_16x16x32_bf16(ones, pb[1], lacc, 0, 0, 0);
#pragma unroll
        for (int f = 0; f < 4; f++) {
            const bf16x8 va0 = *(const bf16x8*)&VsS[f * 1024 + koff];
            const bf16x8 va1 = *(const bf16x8*)&VsS[f * 1024 + (koff ^ 32)];
            O[f] = __builtin_amdgcn_mfma_f32_16x16x32_bf16(va0, pb[0], O[f], 0, 0, 0);
            O[f] = __builtin_amdgcn_mfma_f32_16x16x32_bf16(va1, pb[1], O[f], 0, 0, 0);
        }
        __builtin_amdgcn_s_setprio(0);
    }

    // epilogue: l complete -> normalize, write bf16 attn [b][s][h*64+d].
    const int b_ = bh >> 4;
    const int h_ = bh & 15;
    {
        const float inv = 1.f / lacc[0];
        const int s_ = q0 + wq * 16 + m16;
        unsigned short* orow = attn + ((size_t)b_ * SS + s_) * DD + h_ * HDD;
#pragma unroll
        for (int f = 0; f < 4; f++)
            *(uint2*)(orow + f * 16 + quad * 4) =
                pack4bf(O[f][0] * inv, O[f][1] * inv,
                        O[f][2] * inv, O[f][3] * inv);
    }
}

// ---------------------------------------------------------------------------
// launch
// ---------------------------------------------------------------------------
extern "C" void kernel_launch(void* const* d_in, const int* in_sizes, int n_in,
                              void* d_out, int out_size, void* d_ws, size_t ws_size,
                              hipStream_t stream) {
    const float* x        = (const float*)d_in[0];
    const float* w_qkv    = (const float*)d_in[1];
    const float* b_qkv    = (const float*)d_in[2];
    const float* w_out    = (const float*)d_in[3];
    const float* b_out    = (const float*)d_in[4];
    const float* ln_scale = (const float*)d_in[5];
    const float* ln_bias  = (const float*)d_in[6];
    const float* q_scale  = (const float*)d_in[7];
    const float* k_scale  = (const float*)d_in[8];
    float* out = (float*)d_out;

    char* ws = (char*)d_ws;
    const size_t MB = 1024 * 1024;
    unsigned short* xn    = (unsigned short*)(ws + 0);
    float*          ctab  = (float*)(ws + 9 * MB);
    float*          stab  = (float*)(ws + 10 * MB);
    unsigned short* wqkvT = (unsigned short*)(ws + 64 * MB);
    unsigned short* woutT = (unsigned short*)(ws + 70 * MB);
    unsigned short* qt    = (unsigned short*)(ws + 72 * MB);
    unsigned short* kt    = (unsigned short*)(ws + 80 * MB);
    unsigned short* vt    = (unsigned short*)(ws + 88 * MB);
    unsigned short* vtT   = (unsigned short*)(ws + 96 * MB);
    unsigned short* attn  = (unsigned short*)(ws + 104 * MB);

    const int M = BB * SS;   // 4096

    // fused prep: w_qkv cast (3072 blk) + w_out cast (1024) + rope (256) + ln (4096)
    prep_fused<<<3072 + 1024 + 256 + 4096, 256, 0, stream>>>(
        w_qkv, w_out, x, ln_scale, ln_bias, wqkvT, woutT, ctab, stab, xn);

    // fused QKV GEMM + per-head LN + RoPE -> qt/kt/vt bf16 directly
    gemm_qkv_fused<<<dim3(3 * DD / 128, M / 128), 256, 0, stream>>>(
        xn, wqkvT, b_qkv, q_scale, k_scale, ctab, stab, qt, kt, vt, DD);

    transpose_v<<<BB * HH * (SS / 64), 256, 0, stream>>>(vt, vtT);

    // single-pass attention, split-Q 64 (1024 blocks), bf16 output direct
    attn_mfma<<<dim3(BB * HH * (SS / 64)), 256, 0, stream>>>(qt, kt, vtT, attn);

    // out-projection: 64x128 tile -> 512 blocks = 2/CU, XCD-swizzled
    gemm_out_64<<<dim3(DD / 128, M / 64), 256, 0, stream>>>(attn, woutT, b_out, out,
                                                            M, DD, DD);
}

// Round 18
// 224.623 us; speedup vs baseline: 1.0775x; 1.0256x over previous
//
#include <hip/hip_runtime.h>
#include <math.h>

#define BB 2
#define SS 2048
#define DD 1024
#define HH 16
#define HDD 64
static constexpr float EPS = 1e-6f;

typedef __bf16 bf16x8 __attribute__((ext_vector_type(8)));
typedef __bf16 bf16x4 __attribute__((ext_vector_type(4)));
typedef float f32x4 __attribute__((ext_vector_type(4)));
typedef __attribute__((address_space(1))) const unsigned int gas_u32;
typedef __attribute__((address_space(3))) unsigned int las_u32;

__device__ __forceinline__ unsigned short f2bf(float f) {
    unsigned int u = __float_as_uint(f);
    u = (u + 0x7FFFu + ((u >> 16) & 1u)) >> 16;   // round-to-nearest-even
    return (unsigned short)u;
}

__device__ __forceinline__ uint2 pack4bf(float a, float b, float c, float d) {
    bf16x4 v;
    v[0] = (__bf16)a; v[1] = (__bf16)b; v[2] = (__bf16)c; v[3] = (__bf16)d;
    return *(uint2*)&v;
}

__device__ __forceinline__ void async_ld16(const unsigned short* g, unsigned short* l) {
    __builtin_amdgcn_global_load_lds((gas_u32*)g, (las_u32*)l, 16, 0, 0);
}

// ---------------------------------------------------------------------------
// Kernel 0 (fused prep): one flat grid covering 4 independent sub-kernels:
//   [0,3072)    cast+transpose w_qkv [1024][3072] -> wqkvT [3072][1024]
//   [3072,4096) cast+transpose w_out [1024][1024] -> woutT
//   [4096,4352) RoPE tables
//   [4352,8448) LayerNorm rows of x -> xn (bf16)
// ---------------------------------------------------------------------------
__global__ __launch_bounds__(256) void prep_fused(const float* __restrict__ w_qkv,
                                                  const float* __restrict__ w_out,
                                                  const float* __restrict__ x,
                                                  const float* __restrict__ ln_scale,
                                                  const float* __restrict__ ln_bias,
                                                  unsigned short* __restrict__ wqkvT,
                                                  unsigned short* __restrict__ woutT,
                                                  float* __restrict__ ctab,
                                                  float* __restrict__ stab,
                                                  unsigned short* __restrict__ xn) {
    __shared__ float tile[32][36];
    __shared__ float red[4];
    const int bid = blockIdx.x;
    const int t = threadIdx.x;

    if (bid < 4096) {
        // ---- cast + transpose (w_qkv tiles first, then w_out tiles) ----
        const float* w;
        unsigned short* wt;
        int n0, k0, N;
        if (bid < 3072) {
            w = w_qkv; wt = wqkvT; N = 3 * DD;
            n0 = (bid % 96) * 32;
            k0 = (bid / 96) * 32;
        } else {
            const int idx = bid - 3072;
            w = w_out; wt = woutT; N = DD;
            n0 = (idx % 32) * 32;
            k0 = (idx / 32) * 32;
        }
        const int r = t >> 3;
        const int c = (t & 7) * 4;
        *(float4*)&tile[r][c] = *(const float4*)(w + (size_t)(k0 + r) * N + n0 + c);
        __syncthreads();
        unsigned short o[4];
#pragma unroll
        for (int i = 0; i < 4; i++) o[i] = f2bf(tile[c + i][r]);
        *(uint2*)(wt + (size_t)(n0 + r) * DD + k0 + c) = *(uint2*)o;
    } else if (bid < 4352) {
        // ---- RoPE tables ----
        const int idx = (bid - 4096) * 256 + t;   // 0..65535
        const int s = idx >> 5;
        const int i = idx & 31;
        const float ang = (float)s * exp2f(-(float)i * (13.287712379549449f / 32.f));
        ctab[idx] = cosf(ang);
        stab[idx] = sinf(ang);
    } else {
        // ---- LayerNorm row ----
        const int row = bid - 4352;               // 0..4095
        const float* xr = x + (size_t)row * DD + t * 4;

        float4 v = *(const float4*)xr;
        float s = v.x + v.y + v.z + v.w;
#pragma unroll
        for (int o = 32; o; o >>= 1) s += __shfl_xor(s, o);
        if ((t & 63) == 0) red[t >> 6] = s;
        __syncthreads();
        const float mu = (red[0] + red[1] + red[2] + red[3]) * (1.f / DD);

        float4 d = {v.x - mu, v.y - mu, v.z - mu, v.w - mu};
        float sq = d.x * d.x + d.y * d.y + d.z * d.z + d.w * d.w;
#pragma unroll
        for (int o = 32; o; o >>= 1) sq += __shfl_xor(sq, o);
        __syncthreads();
        if ((t & 63) == 0) red[t >> 6] = sq;
        __syncthreads();
        const float var = (red[0] + red[1] + red[2] + red[3]) * (1.f / DD);
        const float rstd = rsqrtf(var + EPS);

        const float4 sc = *(const float4*)(ln_scale + t * 4);
        const float4 bi = *(const float4*)(ln_bias + t * 4);
        unsigned short o[4];
        o[0] = f2bf(d.x * rstd * sc.x + bi.x);
        o[1] = f2bf(d.y * rstd * sc.y + bi.y);
        o[2] = f2bf(d.z * rstd * sc.z + bi.z);
        o[3] = f2bf(d.w * rstd * sc.w + bi.w);
        *(uint2*)(xn + (size_t)row * DD + t * 4) = *(uint2*)o;
    }
}

// ---------------------------------------------------------------------------
// Kernel 2: out-projection GEMM, 64x128 tile (2 blocks/CU), XCD-swizzled.
// ---------------------------------------------------------------------------
__global__ __launch_bounds__(256) void gemm_out_64(const unsigned short* __restrict__ A,
                                                   const unsigned short* __restrict__ Bt,
                                                   const float* __restrict__ bias,
                                                   float* __restrict__ C,
                                                   int M, int N, int K) {
    __shared__ __align__(16) unsigned short As[64][32];    // 4 KB
    __shared__ __align__(16) unsigned short Bs[128][32];   // 8 KB

    const int flat = blockIdx.y * 8 + blockIdx.x;   // 0..511
    const int swzb = (flat & 7) * 64 + (flat >> 3); // bijective over 512
    const int bm = (swzb >> 3) * 64;
    const int bn = (swzb & 7) * 128;
    const int t = threadIdx.x;
    const int wv = t >> 6;
    const int ln = t & 63;
    const int m16 = ln & 15;
    const int quad = ln >> 4;
    const int wn = wv * 32;

    f32x4 acc[4][2];
#pragma unroll
    for (int i = 0; i < 4; i++)
#pragma unroll
        for (int j = 0; j < 2; j++) acc[i][j] = (f32x4){0.f, 0.f, 0.f, 0.f};

    const int srow = ln >> 2;
    const int sk = (ln & 3) * 8;
    const unsigned short* aptr = A + (size_t)(bm + wv * 16 + srow) * K + sk;
    const unsigned short* bptr0 = Bt + (size_t)(bn + wv * 32 + srow) * K + sk;
    const unsigned short* bptr1 = Bt + (size_t)(bn + wv * 32 + 16 + srow) * K + sk;
    unsigned short* al = &As[wv * 16][0];
    unsigned short* bl0 = &Bs[wv * 32][0];
    unsigned short* bl1 = &Bs[wv * 32 + 16][0];

    for (int k0 = 0; k0 < K; k0 += 32) {
        __syncthreads();
        async_ld16(aptr, al);
        async_ld16(bptr0, bl0);
        async_ld16(bptr1, bl1);
        __syncthreads();

        bf16x8 af[4], bf[2];
#pragma unroll
        for (int i = 0; i < 4; i++)
            af[i] = *(const bf16x8*)&As[i * 16 + m16][quad * 8];
#pragma unroll
        for (int j = 0; j < 2; j++)
            bf[j] = *(const bf16x8*)&Bs[wn + j * 16 + m16][quad * 8];
#pragma unroll
        for (int i = 0; i < 4; i++)
#pragma unroll
            for (int j = 0; j < 2; j++)
                acc[i][j] = __builtin_amdgcn_mfma_f32_16x16x32_bf16(af[i], bf[j], acc[i][j], 0, 0, 0);

        aptr += 32;
        bptr0 += 32;
        bptr1 += 32;
    }

#pragma unroll
    for (int j = 0; j < 2; j++) {
        const int n = bn + wn + j * 16 + m16;
        const float bv = bias[n];
#pragma unroll
        for (int i = 0; i < 4; i++) {
            float* cp = C + (size_t)(bm + i * 16 + quad * 4) * N + n;
#pragma unroll
            for (int r = 0; r < 4; r++)
                cp[(size_t)r * N] = acc[i][j][r] + bv;
        }
    }
}

// ---------------------------------------------------------------------------
// Kernel 2b: fused QKV GEMM + per-head LN + RoPE epilogue -> qt/kt bf16, and
// V written DIRECTLY TRANSPOSED into vtT [b,h,d,s] (same 64 scalar stores as
// the old [b,h,s,d] write; i/r loops fill contiguous 32B s-segments per d-row
// so L2 write-combining keeps HBM traffic at 8 MB). Drops transpose_v.
// XCD-swizzled (bijective over 768).
// ---------------------------------------------------------------------------
__global__ __launch_bounds__(256) void gemm_qkv_fused(const unsigned short* __restrict__ A,
                                                      const unsigned short* __restrict__ Bt,
                                                      const float* __restrict__ bias,
                                                      const float* __restrict__ q_scale,
                                                      const float* __restrict__ k_scale,
                                                      const float* __restrict__ ctab,
                                                      const float* __restrict__ stab,
                                                      unsigned short* __restrict__ qt,
                                                      unsigned short* __restrict__ kt,
                                                      unsigned short* __restrict__ vtT,
                                                      int K) {
    __shared__ __align__(16) unsigned short As[128][32];
    __shared__ __align__(16) unsigned short Bs[128][32];

    const int flat = blockIdx.y * 24 + blockIdx.x;   // 0..767
    const int swzb = (flat & 7) * 96 + (flat >> 3);  // bijective over 768
    const int bm = (swzb / 24) * 128;
    const int bn = (swzb % 24) * 128;
    const int t = threadIdx.x;
    const int wv = t >> 6;
    const int ln = t & 63;
    const int m16 = ln & 15;
    const int quad = ln >> 4;
    const int wm = (wv >> 1) * 64;
    const int wn = (wv & 1) * 64;

    f32x4 acc[4][4];
#pragma unroll
    for (int i = 0; i < 4; i++)
#pragma unroll
        for (int j = 0; j < 4; j++) acc[i][j] = (f32x4){0.f, 0.f, 0.f, 0.f};

    const int srow = wv * 32 + (ln >> 2);
    const int sk = (ln & 3) * 8;
    const unsigned short* aptr = A + (size_t)(bm + srow) * K + sk;
    const unsigned short* bptr = Bt + (size_t)(bn + srow) * K + sk;
    unsigned short* al0 = &As[wv * 32][0];
    unsigned short* al1 = &As[wv * 32 + 16][0];
    unsigned short* bl0 = &Bs[wv * 32][0];
    unsigned short* bl1 = &Bs[wv * 32 + 16][0];

    for (int k0 = 0; k0 < K; k0 += 32) {
        __syncthreads();
        async_ld16(aptr, al0);
        async_ld16(aptr + 16 * (size_t)K, al1);
        async_ld16(bptr, bl0);
        async_ld16(bptr + 16 * (size_t)K, bl1);
        __syncthreads();

        bf16x8 af[4], bf[4];
#pragma unroll
        for (int i = 0; i < 4; i++)
            af[i] = *(const bf16x8*)&As[wm + i * 16 + m16][quad * 8];
#pragma unroll
        for (int j = 0; j < 4; j++)
            bf[j] = *(const bf16x8*)&Bs[wn + j * 16 + m16][quad * 8];
#pragma unroll
        for (int i = 0; i < 4; i++)
#pragma unroll
            for (int j = 0; j < 4; j++)
                acc[i][j] = __builtin_amdgcn_mfma_f32_16x16x32_bf16(af[i], bf[j], acc[i][j], 0, 0, 0);

        aptr += 32;
        bptr += 32;
    }

    // -------- fused epilogue --------
    const int type = bn >> 10;                       // 0=Q, 1=K, 2=V
    const int h = ((bn & 1023) + wn) >> 6;           // this wave's head
    const int rowbase = bm + wm;

    if (type == 2) {
        // V: bias + cast + store TRANSPOSED [b,h,d,s] (d = j*16+m16, s = R)
        float bv[4];
#pragma unroll
        for (int j = 0; j < 4; j++) bv[j] = bias[bn + wn + j * 16 + m16];
#pragma unroll
        for (int i = 0; i < 4; i++) {
#pragma unroll
            for (int r = 0; r < 4; r++) {
                const int R = rowbase + i * 16 + quad * 4 + r;
                const int b_ = R >> 11;
                const int s_ = R & (SS - 1);
                unsigned short* obase =
                    vtT + ((size_t)(b_ * HH + h) * HDD + m16) * SS + s_;
#pragma unroll
                for (int j = 0; j < 4; j++)
                    obase[(size_t)(j * 16) * SS] = f2bf(acc[i][j][r] + bv[j]);
            }
        }
    } else {
        const float* scalp = (type == 0) ? q_scale : k_scale;
        const float outscale = (type == 0) ? 0.18033688011112042f : 1.0f; // 0.125*log2(e)
        unsigned short* dst = (type == 0) ? qt : kt;
        float scl[4], bv[4];
#pragma unroll
        for (int j = 0; j < 4; j++) {
            scl[j] = scalp[j * 16 + m16];
            bv[j] = bias[bn + wn + j * 16 + m16];
        }
#pragma unroll
        for (int i = 0; i < 4; i++) {
#pragma unroll
            for (int r = 0; r < 4; r++) {
                const int R = rowbase + i * 16 + quad * 4 + r;
                const int b_ = R >> 11;
                const int s_ = R & (SS - 1);
                float v0 = acc[i][0][r] + bv[0];
                float v1 = acc[i][1][r] + bv[1];
                float v2 = acc[i][2][r] + bv[2];
                float v3 = acc[i][3][r] + bv[3];
                // per-head LN (no bias): reduce across the 16 lanes of this quad
                float sm = v0 + v1 + v2 + v3;
                sm += __shfl_xor(sm, 1);
                sm += __shfl_xor(sm, 2);
                sm += __shfl_xor(sm, 4);
                sm += __shfl_xor(sm, 8);
                const float mu = sm * (1.f / 64.f);
                v0 -= mu; v1 -= mu; v2 -= mu; v3 -= mu;
                float sq = v0 * v0 + v1 * v1 + v2 * v2 + v3 * v3;
                sq += __shfl_xor(sq, 1);
                sq += __shfl_xor(sq, 2);
                sq += __shfl_xor(sq, 4);
                sq += __shfl_xor(sq, 8);
                const float rstd = rsqrtf(sq * (1.f / 64.f) + EPS);
                v0 *= rstd * scl[0];
                v1 *= rstd * scl[1];
                v2 *= rstd * scl[2];
                v3 *= rstd * scl[3];
                // RoPE: d<32: y*c - y[d+32]*s ; d>=32: y*c + y[d-32]*s
                const float c0 = ctab[s_ * 32 + m16];
                const float s0 = stab[s_ * 32 + m16];
                const float c1 = ctab[s_ * 32 + 16 + m16];
                const float s1 = stab[s_ * 32 + 16 + m16];
                const float o0 = (v0 * c0 - v2 * s0) * outscale;
                const float o1 = (v1 * c1 - v3 * s1) * outscale;
                const float o2 = (v2 * c0 + v0 * s0) * outscale;
                const float o3 = (v3 * c1 + v1 * s1) * outscale;
                unsigned short* orow =
                    dst + (((size_t)(b_ * HH + h) * SS) + s_) * HDD + m16;
                orow[0]  = f2bf(o0);
                orow[16] = f2bf(o1);
                orow[32] = f2bf(o2);
                orow[48] = f2bf(o3);
            }
        }
    }
}

// ---------------------------------------------------------------------------
// Kernel 4: MFMA flash attention, single-pass, split-Q 64-row tiles
// (r10-verified body: 66.6 us). grid 1024 = bh*32 + qtile(64), XCD-swizzled.
// ---------------------------------------------------------------------------
__global__ __launch_bounds__(256, 4) void attn_mfma(const unsigned short* __restrict__ qt,
                                                    const unsigned short* __restrict__ kt,
                                                    const unsigned short* __restrict__ vtT,
                                                    unsigned short* __restrict__ attn) {
    __shared__ __align__(16) unsigned short KsS[64 * 64];     // 8 KB [key][d]
    __shared__ __align__(16) unsigned short VsS[64 * 64];     // 8 KB [d][key]
    __shared__ __align__(16) unsigned short PbS[4][16 * 64];  // 8 KB [q][key]

    const int bid = blockIdx.x;
    const int swz = (bid & 7) * 128 + (bid >> 3);   // bijective over 1024
    const int bh = swz >> 5;
    const int q0 = (swz & 31) * 64;
    const int t = threadIdx.x;
    const int wq = t >> 6;
    const int lane = t & 63;
    const int m16 = lane & 15;
    const int quad = lane >> 4;
    const int m7 = m16 & 7;

    // loop-invariant swizzled offsets
    const int cs = quad ^ m7;
    const int koff = m16 * 64 + cs * 8;             // +g*1024, ^32 for hi chunk
    const int srow = t >> 2;
    const int sch = (t & 3) * 2;
    const int sw0 = srow * 64 + ((sch)     ^ (srow & 7)) * 8;
    const int sw1 = srow * 64 + ((sch + 1) ^ (srow & 7)) * 8;
    const int pwb = m16 * 64 + 4 * (quad & 1);      // P-write base (+chunk*8)
    const int qh = quad >> 1;

    // Q B-fragments (16 q-rows per wave), fixed all kernel
    bf16x8 qb[2];
    {
        const unsigned short* qp =
            qt + ((size_t)bh * SS + q0 + wq * 16 + m16) * HDD + quad * 8;
        qb[0] = *(const bf16x8*)qp;
        qb[1] = *(const bf16x8*)(qp + 32);
    }

    bf16x8 ones;
#pragma unroll
    for (int j = 0; j < 8; j++) ones[j] = (__bf16)1.0f;

    f32x4 O[4];
#pragma unroll
    for (int f = 0; f < 4; f++) O[f] = (f32x4){0.f, 0.f, 0.f, 0.f};
    f32x4 lacc = (f32x4){0.f, 0.f, 0.f, 0.f};

    const unsigned short* kbase = kt + (size_t)bh * SS * HDD;
    const unsigned short* vbase = vtT + (size_t)bh * HDD * SS;
    const f32x4 cinit = (f32x4){-12.f, -12.f, -12.f, -12.f};

    // T14 prologue: issue first K/V tile loads into registers
    uint4 kr0, kr1, vr0, vr1;
    {
        const unsigned short* ksrc = kbase + (size_t)srow * HDD + sch * 8;
        const unsigned short* vsrc = vbase + (size_t)srow * SS + sch * 8;
        kr0 = *(const uint4*)ksrc;
        kr1 = *(const uint4*)(ksrc + 8);
        vr0 = *(const uint4*)vsrc;
        vr1 = *(const uint4*)(vsrc + 8);
    }

    for (int k0 = 0; k0 < SS; k0 += 64) {
        __syncthreads();
        // reg -> LDS (loads for this tile were issued last iteration)
        *(uint4*)&KsS[sw0] = kr0;
        *(uint4*)&KsS[sw1] = kr1;
        *(uint4*)&VsS[sw0] = vr0;
        *(uint4*)&VsS[sw1] = vr1;
        __syncthreads();

        // S^T = K @ Q^T - 12 (C-init)
        f32x4 S[4];
        __builtin_amdgcn_s_setprio(1);
#pragma unroll
        for (int g = 0; g < 4; g++) {
            const bf16x8 ka0 = *(const bf16x8*)&KsS[g * 1024 + koff];
            const bf16x8 ka1 = *(const bf16x8*)&KsS[g * 1024 + (koff ^ 32)];
            f32x4 a = __builtin_amdgcn_mfma_f32_16x16x32_bf16(ka0, qb[0], cinit, 0, 0, 0);
            a = __builtin_amdgcn_mfma_f32_16x16x32_bf16(ka1, qb[1], a, 0, 0, 0);
            S[g] = a;
        }
        __builtin_amdgcn_s_setprio(0);

        // p = exp2(s); packed swizzled P store (per-wave buffer)
#pragma unroll
        for (int g = 0; g < 4; g++) {
            const float p0 = exp2f(S[g][0]);
            const float p1 = exp2f(S[g][1]);
            const float p2 = exp2f(S[g][2]);
            const float p3 = exp2f(S[g][3]);
            *(uint2*)&PbS[wq][pwb + ((2 * g + qh) ^ m7) * 8] =
                pack4bf(p0, p1, p2, p3);
        }

        // T14: S-regs dead — issue NEXT tile's global loads
        if (k0 + 64 < SS) {
            const unsigned short* ksrc = kbase + (size_t)(k0 + 64 + srow) * HDD + sch * 8;
            const unsigned short* vsrc = vbase + (size_t)srow * SS + (k0 + 64) + sch * 8;
            kr0 = *(const uint4*)ksrc;
            kr1 = *(const uint4*)(ksrc + 8);
            vr0 = *(const uint4*)vsrc;
            vr1 = *(const uint4*)(vsrc + 8);
        }

        asm volatile("s_waitcnt lgkmcnt(0)" ::: "memory");

        bf16x8 pb[2];
        pb[0] = *(const bf16x8*)&PbS[wq][koff];
        pb[1] = *(const bf16x8*)&PbS[wq][koff ^ 32];

        // l += row-sums of P (ones-MFMA); O^T += V^T @ P
        __builtin_amdgcn_s_setprio(1);
        lacc = __builtin_amdgcn_mfma_f32_16x16x32_bf16(ones, pb[0], lacc, 0, 0, 0);
        lacc = __builtin_amdgcn_mfma_f32_16x16x32_bf16(ones, pb[1], lacc, 0, 0, 0);
#pragma unroll
        for (int f = 0; f < 4; f++) {
            const bf16x8 va0 = *(const bf16x8*)&VsS[f * 1024 + koff];
            const bf16x8 va1 = *(const bf16x8*)&VsS[f * 1024 + (koff ^ 32)];
            O[f] = __builtin_amdgcn_mfma_f32_16x16x32_bf16(va0, pb[0], O[f], 0, 0, 0);
            O[f] = __builtin_amdgcn_mfma_f32_16x16x32_bf16(va1, pb[1], O[f], 0, 0, 0);
        }
        __builtin_amdgcn_s_setprio(0);
    }

    // epilogue: l complete -> normalize, write bf16 attn [b][s][h*64+d].
    const int b_ = bh >> 4;
    const int h_ = bh & 15;
    {
        const float inv = 1.f / lacc[0];
        const int s_ = q0 + wq * 16 + m16;
        unsigned short* orow = attn + ((size_t)b_ * SS + s_) * DD + h_ * HDD;
#pragma unroll
        for (int f = 0; f < 4; f++)
            *(uint2*)(orow + f * 16 + quad * 4) =
                pack4bf(O[f][0] * inv, O[f][1] * inv,
                        O[f][2] * inv, O[f][3] * inv);
    }
}

// ---------------------------------------------------------------------------
// launch (4 dispatches: prep -> qkv gemm -> attn -> out-proj)
// ---------------------------------------------------------------------------
extern "C" void kernel_launch(void* const* d_in, const int* in_sizes, int n_in,
                              void* d_out, int out_size, void* d_ws, size_t ws_size,
                              hipStream_t stream) {
    const float* x        = (const float*)d_in[0];
    const float* w_qkv    = (const float*)d_in[1];
    const float* b_qkv    = (const float*)d_in[2];
    const float* w_out    = (const float*)d_in[3];
    const float* b_out    = (const float*)d_in[4];
    const float* ln_scale = (const float*)d_in[5];
    const float* ln_bias  = (const float*)d_in[6];
    const float* q_scale  = (const float*)d_in[7];
    const float* k_scale  = (const float*)d_in[8];
    float* out = (float*)d_out;

    char* ws = (char*)d_ws;
    const size_t MB = 1024 * 1024;
    unsigned short* xn    = (unsigned short*)(ws + 0);
    float*          ctab  = (float*)(ws + 9 * MB);
    float*          stab  = (float*)(ws + 10 * MB);
    unsigned short* wqkvT = (unsigned short*)(ws + 64 * MB);
    unsigned short* woutT = (unsigned short*)(ws + 70 * MB);
    unsigned short* qt    = (unsigned short*)(ws + 72 * MB);
    unsigned short* kt    = (unsigned short*)(ws + 80 * MB);
    unsigned short* vtT   = (unsigned short*)(ws + 96 * MB);
    unsigned short* attn  = (unsigned short*)(ws + 104 * MB);

    const int M = BB * SS;   // 4096

    // fused prep: w_qkv cast (3072 blk) + w_out cast (1024) + rope (256) + ln (4096)
    prep_fused<<<3072 + 1024 + 256 + 4096, 256, 0, stream>>>(
        w_qkv, w_out, x, ln_scale, ln_bias, wqkvT, woutT, ctab, stab, xn);

    // fused QKV GEMM + per-head LN + RoPE -> qt/kt bf16; V written transposed
    gemm_qkv_fused<<<dim3(3 * DD / 128, M / 128), 256, 0, stream>>>(
        xn, wqkvT, b_qkv, q_scale, k_scale, ctab, stab, qt, kt, vtT, DD);

    // single-pass attention, split-Q 64 (1024 blocks), bf16 output direct
    attn_mfma<<<dim3(BB * HH * (SS / 64)), 256, 0, stream>>>(qt, kt, vtT, attn);

    // out-projection: 64x128 tile -> 512 blocks = 2/CU, XCD-swizzled
    gemm_out_64<<<dim3(DD / 128, M / 64), 256, 0, stream>>>(attn, woutT, b_out, out,
                                                            M, DD, DD);
}

// Round 19
// 218.126 us; speedup vs baseline: 1.1096x; 1.0298x over previous
//
#include <hip/hip_runtime.h>
#include <math.h>

#define BB 2
#define SS 2048
#define DD 1024
#define HH 16
#define HDD 64
static constexpr float EPS = 1e-6f;

typedef __bf16 bf16x8 __attribute__((ext_vector_type(8)));
typedef __bf16 bf16x4 __attribute__((ext_vector_type(4)));
typedef float f32x4 __attribute__((ext_vector_type(4)));
typedef __attribute__((address_space(1))) const unsigned int gas_u32;
typedef __attribute__((address_space(3))) unsigned int las_u32;

__device__ __forceinline__ unsigned short f2bf(float f) {
    unsigned int u = __float_as_uint(f);
    u = (u + 0x7FFFu + ((u >> 16) & 1u)) >> 16;   // round-to-nearest-even
    return (unsigned short)u;
}

__device__ __forceinline__ uint2 pack4bf(float a, float b, float c, float d) {
    bf16x4 v;
    v[0] = (__bf16)a; v[1] = (__bf16)b; v[2] = (__bf16)c; v[3] = (__bf16)d;
    return *(uint2*)&v;
}

__device__ __forceinline__ void async_ld16(const unsigned short* g, unsigned short* l) {
    __builtin_amdgcn_global_load_lds((gas_u32*)g, (las_u32*)l, 16, 0, 0);
}

// ---------------------------------------------------------------------------
// Kernel 0 (fused prep): one flat grid covering 4 independent sub-kernels:
//   [0,3072)    cast+transpose w_qkv [1024][3072] -> wqkvT [3072][1024]
//   [3072,4096) cast+transpose w_out [1024][1024] -> woutT
//   [4096,4352) RoPE tables
//   [4352,8448) LayerNorm rows of x -> xn (bf16)
// ---------------------------------------------------------------------------
__global__ __launch_bounds__(256) void prep_fused(const float* __restrict__ w_qkv,
                                                  const float* __restrict__ w_out,
                                                  const float* __restrict__ x,
                                                  const float* __restrict__ ln_scale,
                                                  const float* __restrict__ ln_bias,
                                                  unsigned short* __restrict__ wqkvT,
                                                  unsigned short* __restrict__ woutT,
                                                  float* __restrict__ ctab,
                                                  float* __restrict__ stab,
                                                  unsigned short* __restrict__ xn) {
    __shared__ float tile[32][36];
    __shared__ float red[4];
    const int bid = blockIdx.x;
    const int t = threadIdx.x;

    if (bid < 4096) {
        // ---- cast + transpose (w_qkv tiles first, then w_out tiles) ----
        const float* w;
        unsigned short* wt;
        int n0, k0, N;
        if (bid < 3072) {
            w = w_qkv; wt = wqkvT; N = 3 * DD;
            n0 = (bid % 96) * 32;
            k0 = (bid / 96) * 32;
        } else {
            const int idx = bid - 3072;
            w = w_out; wt = woutT; N = DD;
            n0 = (idx % 32) * 32;
            k0 = (idx / 32) * 32;
        }
        const int r = t >> 3;
        const int c = (t & 7) * 4;
        *(float4*)&tile[r][c] = *(const float4*)(w + (size_t)(k0 + r) * N + n0 + c);
        __syncthreads();
        unsigned short o[4];
#pragma unroll
        for (int i = 0; i < 4; i++) o[i] = f2bf(tile[c + i][r]);
        *(uint2*)(wt + (size_t)(n0 + r) * DD + k0 + c) = *(uint2*)o;
    } else if (bid < 4352) {
        // ---- RoPE tables ----
        const int idx = (bid - 4096) * 256 + t;   // 0..65535
        const int s = idx >> 5;
        const int i = idx & 31;
        const float ang = (float)s * exp2f(-(float)i * (13.287712379549449f / 32.f));
        ctab[idx] = cosf(ang);
        stab[idx] = sinf(ang);
    } else {
        // ---- LayerNorm row ----
        const int row = bid - 4352;               // 0..4095
        const float* xr = x + (size_t)row * DD + t * 4;

        float4 v = *(const float4*)xr;
        float s = v.x + v.y + v.z + v.w;
#pragma unroll
        for (int o = 32; o; o >>= 1) s += __shfl_xor(s, o);
        if ((t & 63) == 0) red[t >> 6] = s;
        __syncthreads();
        const float mu = (red[0] + red[1] + red[2] + red[3]) * (1.f / DD);

        float4 d = {v.x - mu, v.y - mu, v.z - mu, v.w - mu};
        float sq = d.x * d.x + d.y * d.y + d.z * d.z + d.w * d.w;
#pragma unroll
        for (int o = 32; o; o >>= 1) sq += __shfl_xor(sq, o);
        __syncthreads();
        if ((t & 63) == 0) red[t >> 6] = sq;
        __syncthreads();
        const float var = (red[0] + red[1] + red[2] + red[3]) * (1.f / DD);
        const float rstd = rsqrtf(var + EPS);

        const float4 sc = *(const float4*)(ln_scale + t * 4);
        const float4 bi = *(const float4*)(ln_bias + t * 4);
        unsigned short o[4];
        o[0] = f2bf(d.x * rstd * sc.x + bi.x);
        o[1] = f2bf(d.y * rstd * sc.y + bi.y);
        o[2] = f2bf(d.z * rstd * sc.z + bi.z);
        o[3] = f2bf(d.w * rstd * sc.w + bi.w);
        *(uint2*)(xn + (size_t)row * DD + t * 4) = *(uint2*)o;
    }
}

// ---------------------------------------------------------------------------
// Kernel 2: out-projection GEMM, 64x128 tile (2 blocks/CU), XCD-swizzled.
// ---------------------------------------------------------------------------
__global__ __launch_bounds__(256) void gemm_out_64(const unsigned short* __restrict__ A,
                                                   const unsigned short* __restrict__ Bt,
                                                   const float* __restrict__ bias,
                                                   float* __restrict__ C,
                                                   int M, int N, int K) {
    __shared__ __align__(16) unsigned short As[64][32];    // 4 KB
    __shared__ __align__(16) unsigned short Bs[128][32];   // 8 KB

    const int flat = blockIdx.y * 8 + blockIdx.x;   // 0..511
    const int swzb = (flat & 7) * 64 + (flat >> 3); // bijective over 512
    const int bm = (swzb >> 3) * 64;
    const int bn = (swzb & 7) * 128;
    const int t = threadIdx.x;
    const int wv = t >> 6;
    const int ln = t & 63;
    const int m16 = ln & 15;
    const int quad = ln >> 4;
    const int wn = wv * 32;

    f32x4 acc[4][2];
#pragma unroll
    for (int i = 0; i < 4; i++)
#pragma unroll
        for (int j = 0; j < 2; j++) acc[i][j] = (f32x4){0.f, 0.f, 0.f, 0.f};

    const int srow = ln >> 2;
    const int sk = (ln & 3) * 8;
    const unsigned short* aptr = A + (size_t)(bm + wv * 16 + srow) * K + sk;
    const unsigned short* bptr0 = Bt + (size_t)(bn + wv * 32 + srow) * K + sk;
    const unsigned short* bptr1 = Bt + (size_t)(bn + wv * 32 + 16 + srow) * K + sk;
    unsigned short* al = &As[wv * 16][0];
    unsigned short* bl0 = &Bs[wv * 32][0];
    unsigned short* bl1 = &Bs[wv * 32 + 16][0];

    for (int k0 = 0; k0 < K; k0 += 32) {
        __syncthreads();
        async_ld16(aptr, al);
        async_ld16(bptr0, bl0);
        async_ld16(bptr1, bl1);
        __syncthreads();

        bf16x8 af[4], bf[2];
#pragma unroll
        for (int i = 0; i < 4; i++)
            af[i] = *(const bf16x8*)&As[i * 16 + m16][quad * 8];
#pragma unroll
        for (int j = 0; j < 2; j++)
            bf[j] = *(const bf16x8*)&Bs[wn + j * 16 + m16][quad * 8];
#pragma unroll
        for (int i = 0; i < 4; i++)
#pragma unroll
            for (int j = 0; j < 2; j++)
                acc[i][j] = __builtin_amdgcn_mfma_f32_16x16x32_bf16(af[i], bf[j], acc[i][j], 0, 0, 0);

        aptr += 32;
        bptr0 += 32;
        bptr1 += 32;
    }

#pragma unroll
    for (int j = 0; j < 2; j++) {
        const int n = bn + wn + j * 16 + m16;
        const float bv = bias[n];
#pragma unroll
        for (int i = 0; i < 4; i++) {
            float* cp = C + (size_t)(bm + i * 16 + quad * 4) * N + n;
#pragma unroll
            for (int r = 0; r < 4; r++)
                cp[(size_t)r * N] = acc[i][j][r] + bv;
        }
    }
}

// ---------------------------------------------------------------------------
// Kernel 2b: fused QKV GEMM, 128x64 tile (BN = one head) -> 1536 blocks =
// 6 blocks/CU = 24 waves/CU (was 768/3/12 — mirror of r12's verified
// out-proj tile shrink). Wave wv owns rows wv*32..+31, all 64 cols:
// acc[2][4]. Per-head LN/RoPE epilogue mapping unchanged (d = j*16+m16,
// one head per block). V written directly transposed into vtT [b,h,d,s].
// XCD-swizzled (bijective over 1536).
// ---------------------------------------------------------------------------
__global__ __launch_bounds__(256) void gemm_qkv_fused(const unsigned short* __restrict__ A,
                                                      const unsigned short* __restrict__ Bt,
                                                      const float* __restrict__ bias,
                                                      const float* __restrict__ q_scale,
                                                      const float* __restrict__ k_scale,
                                                      const float* __restrict__ ctab,
                                                      const float* __restrict__ stab,
                                                      unsigned short* __restrict__ qt,
                                                      unsigned short* __restrict__ kt,
                                                      unsigned short* __restrict__ vtT,
                                                      int K) {
    __shared__ __align__(16) unsigned short As[128][32];   // 8 KB
    __shared__ __align__(16) unsigned short Bs[64][32];    // 4 KB

    const int flat = blockIdx.y * 48 + blockIdx.x;    // 0..1535
    const int swzb = (flat & 7) * 192 + (flat >> 3);  // bijective over 1536
    const int bm = (swzb / 48) * 128;
    const int bn = (swzb % 48) * 64;
    const int t = threadIdx.x;
    const int wv = t >> 6;
    const int ln = t & 63;
    const int m16 = ln & 15;
    const int quad = ln >> 4;
    const int wm = wv * 32;

    f32x4 acc[2][4];
#pragma unroll
    for (int i = 0; i < 2; i++)
#pragma unroll
        for (int j = 0; j < 4; j++) acc[i][j] = (f32x4){0.f, 0.f, 0.f, 0.f};

    const int srow = ln >> 2;              // 0..15 within a 16-row slab
    const int sk = (ln & 3) * 8;
    const unsigned short* aptr = A + (size_t)(bm + wv * 32 + srow) * K + sk;
    const unsigned short* bptr = Bt + (size_t)(bn + wv * 16 + srow) * K + sk;
    unsigned short* al0 = &As[wv * 32][0];
    unsigned short* al1 = &As[wv * 32 + 16][0];
    unsigned short* bl = &Bs[wv * 16][0];

    for (int k0 = 0; k0 < K; k0 += 32) {
        __syncthreads();
        async_ld16(aptr, al0);
        async_ld16(aptr + 16 * (size_t)K, al1);
        async_ld16(bptr, bl);
        __syncthreads();

        bf16x8 af[2], bf[4];
#pragma unroll
        for (int i = 0; i < 2; i++)
            af[i] = *(const bf16x8*)&As[wm + i * 16 + m16][quad * 8];
#pragma unroll
        for (int j = 0; j < 4; j++)
            bf[j] = *(const bf16x8*)&Bs[j * 16 + m16][quad * 8];
#pragma unroll
        for (int i = 0; i < 2; i++)
#pragma unroll
            for (int j = 0; j < 4; j++)
                acc[i][j] = __builtin_amdgcn_mfma_f32_16x16x32_bf16(af[i], bf[j], acc[i][j], 0, 0, 0);

        aptr += 32;
        bptr += 32;
    }

    // -------- fused epilogue (one head per block) --------
    const int type = bn >> 10;                       // 0=Q, 1=K, 2=V
    const int h = (bn & 1023) >> 6;                  // this block's head
    const int rowbase = bm + wm;

    if (type == 2) {
        // V: bias + cast + store TRANSPOSED [b,h,d,s] (d = j*16+m16, s = R)
        float bv[4];
#pragma unroll
        for (int j = 0; j < 4; j++) bv[j] = bias[bn + j * 16 + m16];
#pragma unroll
        for (int i = 0; i < 2; i++) {
#pragma unroll
            for (int r = 0; r < 4; r++) {
                const int R = rowbase + i * 16 + quad * 4 + r;
                const int b_ = R >> 11;
                const int s_ = R & (SS - 1);
                unsigned short* obase =
                    vtT + ((size_t)(b_ * HH + h) * HDD + m16) * SS + s_;
#pragma unroll
                for (int j = 0; j < 4; j++)
                    obase[(size_t)(j * 16) * SS] = f2bf(acc[i][j][r] + bv[j]);
            }
        }
    } else {
        const float* scalp = (type == 0) ? q_scale : k_scale;
        const float outscale = (type == 0) ? 0.18033688011112042f : 1.0f; // 0.125*log2(e)
        unsigned short* dst = (type == 0) ? qt : kt;
        float scl[4], bv[4];
#pragma unroll
        for (int j = 0; j < 4; j++) {
            scl[j] = scalp[j * 16 + m16];
            bv[j] = bias[bn + j * 16 + m16];
        }
#pragma unroll
        for (int i = 0; i < 2; i++) {
#pragma unroll
            for (int r = 0; r < 4; r++) {
                const int R = rowbase + i * 16 + quad * 4 + r;
                const int b_ = R >> 11;
                const int s_ = R & (SS - 1);
                float v0 = acc[i][0][r] + bv[0];
                float v1 = acc[i][1][r] + bv[1];
                float v2 = acc[i][2][r] + bv[2];
                float v3 = acc[i][3][r] + bv[3];
                // per-head LN (no bias): reduce across the 16 lanes of this quad
                float sm = v0 + v1 + v2 + v3;
                sm += __shfl_xor(sm, 1);
                sm += __shfl_xor(sm, 2);
                sm += __shfl_xor(sm, 4);
                sm += __shfl_xor(sm, 8);
                const float mu = sm * (1.f / 64.f);
                v0 -= mu; v1 -= mu; v2 -= mu; v3 -= mu;
                float sq = v0 * v0 + v1 * v1 + v2 * v2 + v3 * v3;
                sq += __shfl_xor(sq, 1);
                sq += __shfl_xor(sq, 2);
                sq += __shfl_xor(sq, 4);
                sq += __shfl_xor(sq, 8);
                const float rstd = rsqrtf(sq * (1.f / 64.f) + EPS);
                v0 *= rstd * scl[0];
                v1 *= rstd * scl[1];
                v2 *= rstd * scl[2];
                v3 *= rstd * scl[3];
                // RoPE: d<32: y*c - y[d+32]*s ; d>=32: y*c + y[d-32]*s
                const float c0 = ctab[s_ * 32 + m16];
                const float s0 = stab[s_ * 32 + m16];
                const float c1 = ctab[s_ * 32 + 16 + m16];
                const float s1 = stab[s_ * 32 + 16 + m16];
                const float o0 = (v0 * c0 - v2 * s0) * outscale;
                const float o1 = (v1 * c1 - v3 * s1) * outscale;
                const float o2 = (v2 * c0 + v0 * s0) * outscale;
                const float o3 = (v3 * c1 + v1 * s1) * outscale;
                unsigned short* orow =
                    dst + (((size_t)(b_ * HH + h) * SS) + s_) * HDD + m16;
                orow[0]  = f2bf(o0);
                orow[16] = f2bf(o1);
                orow[32] = f2bf(o2);
                orow[48] = f2bf(o3);
            }
        }
    }
}

// ---------------------------------------------------------------------------
// Kernel 4: MFMA flash attention, single-pass, split-Q 64-row tiles
// (r10-verified body: 66.6 us). grid 1024 = bh*32 + qtile(64), XCD-swizzled.
// ---------------------------------------------------------------------------
__global__ __launch_bounds__(256, 4) void attn_mfma(const unsigned short* __restrict__ qt,
                                                    const unsigned short* __restrict__ kt,
                                                    const unsigned short* __restrict__ vtT,
                                                    unsigned short* __restrict__ attn) {
    __shared__ __align__(16) unsigned short KsS[64 * 64];     // 8 KB [key][d]
    __shared__ __align__(16) unsigned short VsS[64 * 64];     // 8 KB [d][key]
    __shared__ __align__(16) unsigned short PbS[4][16 * 64];  // 8 KB [q][key]

    const int bid = blockIdx.x;
    const int swz = (bid & 7) * 128 + (bid >> 3);   // bijective over 1024
    const int bh = swz >> 5;
    const int q0 = (swz & 31) * 64;
    const int t = threadIdx.x;
    const int wq = t >> 6;
    const int lane = t & 63;
    const int m16 = lane & 15;
    const int quad = lane >> 4;
    const int m7 = m16 & 7;

    // loop-invariant swizzled offsets
    const int cs = quad ^ m7;
    const int koff = m16 * 64 + cs * 8;             // +g*1024, ^32 for hi chunk
    const int srow = t >> 2;
    const int sch = (t & 3) * 2;
    const int sw0 = srow * 64 + ((sch)     ^ (srow & 7)) * 8;
    const int sw1 = srow * 64 + ((sch + 1) ^ (srow & 7)) * 8;
    const int pwb = m16 * 64 + 4 * (quad & 1);      // P-write base (+chunk*8)
    const int qh = quad >> 1;

    // Q B-fragments (16 q-rows per wave), fixed all kernel
    bf16x8 qb[2];
    {
        const unsigned short* qp =
            qt + ((size_t)bh * SS + q0 + wq * 16 + m16) * HDD + quad * 8;
        qb[0] = *(const bf16x8*)qp;
        qb[1] = *(const bf16x8*)(qp + 32);
    }

    bf16x8 ones;
#pragma unroll
    for (int j = 0; j < 8; j++) ones[j] = (__bf16)1.0f;

    f32x4 O[4];
#pragma unroll
    for (int f = 0; f < 4; f++) O[f] = (f32x4){0.f, 0.f, 0.f, 0.f};
    f32x4 lacc = (f32x4){0.f, 0.f, 0.f, 0.f};

    const unsigned short* kbase = kt + (size_t)bh * SS * HDD;
    const unsigned short* vbase = vtT + (size_t)bh * HDD * SS;
    const f32x4 cinit = (f32x4){-12.f, -12.f, -12.f, -12.f};

    // T14 prologue: issue first K/V tile loads into registers
    uint4 kr0, kr1, vr0, vr1;
    {
        const unsigned short* ksrc = kbase + (size_t)srow * HDD + sch * 8;
        const unsigned short* vsrc = vbase + (size_t)srow * SS + sch * 8;
        kr0 = *(const uint4*)ksrc;
        kr1 = *(const uint4*)(ksrc + 8);
        vr0 = *(const uint4*)vsrc;
        vr1 = *(const uint4*)(vsrc + 8);
    }

    for (int k0 = 0; k0 < SS; k0 += 64) {
        __syncthreads();
        // reg -> LDS (loads for this tile were issued last iteration)
        *(uint4*)&KsS[sw0] = kr0;
        *(uint4*)&KsS[sw1] = kr1;
        *(uint4*)&VsS[sw0] = vr0;
        *(uint4*)&VsS[sw1] = vr1;
        __syncthreads();

        // S^T = K @ Q^T - 12 (C-init)
        f32x4 S[4];
        __builtin_amdgcn_s_setprio(1);
#pragma unroll
        for (int g = 0; g < 4; g++) {
            const bf16x8 ka0 = *(const bf16x8*)&KsS[g * 1024 + koff];
            const bf16x8 ka1 = *(const bf16x8*)&KsS[g * 1024 + (koff ^ 32)];
            f32x4 a = __builtin_amdgcn_mfma_f32_16x16x32_bf16(ka0, qb[0], cinit, 0, 0, 0);
            a = __builtin_amdgcn_mfma_f32_16x16x32_bf16(ka1, qb[1], a, 0, 0, 0);
            S[g] = a;
        }
        __builtin_amdgcn_s_setprio(0);

        // p = exp2(s); packed swizzled P store (per-wave buffer)
#pragma unroll
        for (int g = 0; g < 4; g++) {
            const float p0 = exp2f(S[g][0]);
            const float p1 = exp2f(S[g][1]);
            const float p2 = exp2f(S[g][2]);
            const float p3 = exp2f(S[g][3]);
            *(uint2*)&PbS[wq][pwb + ((2 * g + qh) ^ m7) * 8] =
                pack4bf(p0, p1, p2, p3);
        }

        // T14: S-regs dead — issue NEXT tile's global loads
        if (k0 + 64 < SS) {
            const unsigned short* ksrc = kbase + (size_t)(k0 + 64 + srow) * HDD + sch * 8;
            const unsigned short* vsrc = vbase + (size_t)srow * SS + (k0 + 64) + sch * 8;
            kr0 = *(const uint4*)ksrc;
            kr1 = *(const uint4*)(ksrc + 8);
            vr0 = *(const uint4*)vsrc;
            vr1 = *(const uint4*)(vsrc + 8);
        }

        asm volatile("s_waitcnt lgkmcnt(0)" ::: "memory");

        bf16x8 pb[2];
        pb[0] = *(const bf16x8*)&PbS[wq][koff];
        pb[1] = *(const bf16x8*)&PbS[wq][koff ^ 32];

        // l += row-sums of P (ones-MFMA); O^T += V^T @ P
        __builtin_amdgcn_s_setprio(1);
        lacc = __builtin_amdgcn_mfma_f32_16x16x32_bf16(ones, pb[0], lacc, 0, 0, 0);
        lacc = __builtin_amdgcn_mfma_f32_16x16x32_bf16(ones, pb[1], lacc, 0, 0, 0);
#pragma unroll
        for (int f = 0; f < 4; f++) {
            const bf16x8 va0 = *(const bf16x8*)&VsS[f * 1024 + koff];
            const bf16x8 va1 = *(const bf16x8*)&VsS[f * 1024 + (koff ^ 32)];
            O[f] = __builtin_amdgcn_mfma_f32_16x16x32_bf16(va0, pb[0], O[f], 0, 0, 0);
            O[f] = __builtin_amdgcn_mfma_f32_16x16x32_bf16(va1, pb[1], O[f], 0, 0, 0);
        }
        __builtin_amdgcn_s_setprio(0);
    }

    // epilogue: l complete -> normalize, write bf16 attn [b][s][h*64+d].
    const int b_ = bh >> 4;
    const int h_ = bh & 15;
    {
        const float inv = 1.f / lacc[0];
        const int s_ = q0 + wq * 16 + m16;
        unsigned short* orow = attn + ((size_t)b_ * SS + s_) * DD + h_ * HDD;
#pragma unroll
        for (int f = 0; f < 4; f++)
            *(uint2*)(orow + f * 16 + quad * 4) =
                pack4bf(O[f][0] * inv, O[f][1] * inv,
                        O[f][2] * inv, O[f][3] * inv);
    }
}

// ---------------------------------------------------------------------------
// launch (4 dispatches: prep -> qkv gemm -> attn -> out-proj)
// ---------------------------------------------------------------------------
extern "C" void kernel_launch(void* const* d_in, const int* in_sizes, int n_in,
                              void* d_out, int out_size, void* d_ws, size_t ws_size,
                              hipStream_t stream) {
    const float* x        = (const float*)d_in[0];
    const float* w_qkv    = (const float*)d_in[1];
    const float* b_qkv    = (const float*)d_in[2];
    const float* w_out    = (const float*)d_in[3];
    const float* b_out    = (const float*)d_in[4];
    const float* ln_scale = (const float*)d_in[5];
    const float* ln_bias  = (const float*)d_in[6];
    const float* q_scale  = (const float*)d_in[7];
    const float* k_scale  = (const float*)d_in[8];
    float* out = (float*)d_out;

    char* ws = (char*)d_ws;
    const size_t MB = 1024 * 1024;
    unsigned short* xn    = (unsigned short*)(ws + 0);
    float*          ctab  = (float*)(ws + 9 * MB);
    float*          stab  = (float*)(ws + 10 * MB);
    unsigned short* wqkvT = (unsigned short*)(ws + 64 * MB);
    unsigned short* woutT = (unsigned short*)(ws + 70 * MB);
    unsigned short* qt    = (unsigned short*)(ws + 72 * MB);
    unsigned short* kt    = (unsigned short*)(ws + 80 * MB);
    unsigned short* vtT   = (unsigned short*)(ws + 96 * MB);
    unsigned short* attn  = (unsigned short*)(ws + 104 * MB);

    const int M = BB * SS;   // 4096

    // fused prep: w_qkv cast (3072 blk) + w_out cast (1024) + rope (256) + ln (4096)
    prep_fused<<<3072 + 1024 + 256 + 4096, 256, 0, stream>>>(
        w_qkv, w_out, x, ln_scale, ln_bias, wqkvT, woutT, ctab, stab, xn);

    // fused QKV GEMM (128x64 tile, 1536 blocks = 6/CU) + LN/RoPE epilogue
    gemm_qkv_fused<<<dim3(3 * DD / 64, M / 128), 256, 0, stream>>>(
        xn, wqkvT, b_qkv, q_scale, k_scale, ctab, stab, qt, kt, vtT, DD);

    // single-pass attention, split-Q 64 (1024 blocks), bf16 output direct
    attn_mfma<<<dim3(BB * HH * (SS / 64)), 256, 0, stream>>>(qt, kt, vtT, attn);

    // out-projection: 64x128 tile -> 512 blocks = 2/CU, XCD-swizzled
    gemm_out_64<<<dim3(DD / 128, M / 64), 256, 0, stream>>>(attn, woutT, b_out, out,
                                                            M, DD, DD);
}